// Round 1
// baseline (239.256 us; speedup 1.0000x reference)
//
#include <hip/hip_runtime.h>
#include <hip/hip_bf16.h>
#include <math.h>

#define N_NODES 10000
#define N_EDGES 320000
#define NFEAT   512
#define NHID    256
#define NCLASS  40

// ---------------- CSR build (bucket edges by dst) ----------------

__global__ __launch_bounds__(256) void count_k(const int* __restrict__ dst,
                                               int* __restrict__ deg) {
  int e = blockIdx.x * 256 + threadIdx.x;
  if (e < N_EDGES) atomicAdd(&deg[dst[e]], 1);
}

__global__ __launch_bounds__(256) void scan_k(const int* __restrict__ deg,
                                              int* __restrict__ rp,
                                              int* __restrict__ nxt) {
  __shared__ int part[256];
  int t = threadIdx.x;
  const int CH = 40;                    // 256*40 = 10240 >= 10000
  int lo = t * CH, hi = lo + CH;
  if (lo > N_NODES) lo = N_NODES;
  if (hi > N_NODES) hi = N_NODES;
  int s = 0;
  for (int j = lo; j < hi; j++) s += deg[j];
  part[t] = s;
  __syncthreads();
  if (t == 0) {
    int r = 0;
    for (int j = 0; j < 256; j++) { int v = part[j]; part[j] = r; r += v; }
  }
  __syncthreads();
  int r = part[t];
  for (int j = lo; j < hi; j++) { rp[j] = r; nxt[j] = r; r += deg[j]; }
  if (t == 255) rp[N_NODES] = r;        // = N_EDGES
}

__global__ __launch_bounds__(256) void scatter_k(const int* __restrict__ src,
                                                 const int* __restrict__ dst,
                                                 const float* __restrict__ w,
                                                 int* __restrict__ nxt,
                                                 int* __restrict__ esrc,
                                                 float* __restrict__ ew) {
  int e = blockIdx.x * 256 + threadIdx.x;
  if (e < N_EDGES) {
    int d = dst[e];
    int p = atomicAdd(&nxt[d], 1);
    esrc[p] = src[e];
    ew[p]   = w[e];
  }
}

// ---------------- GEMM1: xw1 = x @ W1  (10000x512 @ 512x256) ----------------
// 64x64 tile, BK=16, 256 threads, 4x4 per thread, float4 LDS reads.

__global__ __launch_bounds__(256) void gemm1_k(const float* __restrict__ A,
                                               const float* __restrict__ B,
                                               float* __restrict__ C) {
  const int M = N_NODES, K = NFEAT, N = NHID;
  __shared__ float As[16][68];   // [k][m], pad 68 keeps 16B alignment, ~2-way banks
  __shared__ float Bs[16][68];   // [k][n]

  const int bm = blockIdx.x * 64;
  const int bn = blockIdx.y * 64;
  const int t  = threadIdx.x;
  const int ty = t >> 4;         // 0..15 -> row group
  const int tx = t & 15;         // 0..15 -> col group

  // A-load mapping: thread t loads row ar (0..63), k-quad ak (0,4,8,12)
  const int ar = t >> 2;
  const int ak = (t & 3) * 4;
  // B-load mapping: thread t loads k-row bk (0..15), 4 cols at bn4
  const int bk  = t >> 4;
  const int bn4 = (t & 15) * 4;

  float acc[4][4] = {};

  for (int k0 = 0; k0 < K; k0 += 16) {
    int arow = bm + ar;
    float4 av;
    if (arow < M) av = *(const float4*)&A[(size_t)arow * K + k0 + ak];
    else          av = make_float4(0.f, 0.f, 0.f, 0.f);
    As[ak + 0][ar] = av.x;
    As[ak + 1][ar] = av.y;
    As[ak + 2][ar] = av.z;
    As[ak + 3][ar] = av.w;

    float4 bv = *(const float4*)&B[(size_t)(k0 + bk) * N + bn + bn4];
    *(float4*)&Bs[bk][bn4] = bv;

    __syncthreads();

#pragma unroll
    for (int k = 0; k < 16; k++) {
      float4 a4 = *(const float4*)&As[k][ty * 4];
      float4 b4 = *(const float4*)&Bs[k][tx * 4];
      acc[0][0] += a4.x * b4.x; acc[0][1] += a4.x * b4.y; acc[0][2] += a4.x * b4.z; acc[0][3] += a4.x * b4.w;
      acc[1][0] += a4.y * b4.x; acc[1][1] += a4.y * b4.y; acc[1][2] += a4.y * b4.z; acc[1][3] += a4.y * b4.w;
      acc[2][0] += a4.z * b4.x; acc[2][1] += a4.z * b4.y; acc[2][2] += a4.z * b4.z; acc[2][3] += a4.z * b4.w;
      acc[3][0] += a4.w * b4.x; acc[3][1] += a4.w * b4.y; acc[3][2] += a4.w * b4.z; acc[3][3] += a4.w * b4.w;
    }
    __syncthreads();
  }

#pragma unroll
  for (int i = 0; i < 4; i++) {
    int m = bm + ty * 4 + i;
    if (m < M) {
      float4 o = make_float4(acc[i][0], acc[i][1], acc[i][2], acc[i][3]);
      *(float4*)&C[(size_t)m * N + bn + tx * 4] = o;
    }
  }
}

// ---------------- SpMM1: h = relu(A_csr * xw1 + b1) ----------------
// one block per dst row, thread-per-feature (256 feats)

__global__ __launch_bounds__(256) void spmm1_k(const int* __restrict__ rp,
                                               const int* __restrict__ esrc,
                                               const float* __restrict__ ew,
                                               const float* __restrict__ xw1,
                                               const float* __restrict__ b1,
                                               float* __restrict__ h) {
  int i = blockIdx.x;
  int f = threadIdx.x;
  int e0 = rp[i], e1 = rp[i + 1];
  float acc = 0.f;
  for (int e = e0; e < e1; e++) {
    int s   = esrc[e];
    float w = ew[e];
    acc += w * xw1[(size_t)s * NHID + f];
  }
  acc += b1[f];
  h[(size_t)i * NHID + f] = fmaxf(acc, 0.f);
}

// ---------------- GEMM2: hw2 = h @ W2  (10000x256 @ 256x40) ----------------

__global__ __launch_bounds__(256) void gemm2_k(const float* __restrict__ h,
                                               const float* __restrict__ W2,
                                               float* __restrict__ hw2) {
  int t  = threadIdx.x;
  int c  = t & 63;               // class lane (active < 40)
  int ty = t >> 6;               // 0..3
  int r0 = blockIdx.x * 16 + ty * 4;
  bool act = (c < NCLASS);
  float acc0 = 0.f, acc1 = 0.f, acc2 = 0.f, acc3 = 0.f;
  const float* h0 = h + (size_t)r0 * NHID;
  for (int k = 0; k < NHID; k++) {
    float w = act ? W2[k * NCLASS + c] : 0.f;
    float x0 = h0[k];
    float x1 = h0[NHID + k];
    float x2 = h0[2 * NHID + k];
    float x3 = h0[3 * NHID + k];
    acc0 += x0 * w; acc1 += x1 * w; acc2 += x2 * w; acc3 += x3 * w;
  }
  if (act) {
    hw2[(size_t)(r0 + 0) * NCLASS + c] = acc0;
    hw2[(size_t)(r0 + 1) * NCLASS + c] = acc1;
    hw2[(size_t)(r0 + 2) * NCLASS + c] = acc2;
    hw2[(size_t)(r0 + 3) * NCLASS + c] = acc3;
  }
}

// ---------------- SpMM2 + b2 + log_softmax -> out ----------------
// one wave per dst row

__global__ __launch_bounds__(64) void spmm2_k(const int* __restrict__ rp,
                                              const int* __restrict__ esrc,
                                              const float* __restrict__ ew,
                                              const float* __restrict__ hw2,
                                              const float* __restrict__ b2,
                                              float* __restrict__ out) {
  int i    = blockIdx.x;
  int lane = threadIdx.x;
  bool act = (lane < NCLASS);
  int e0 = rp[i], e1 = rp[i + 1];
  float acc = act ? b2[lane] : 0.f;
  if (act) {
    for (int e = e0; e < e1; e++) {
      int s   = esrc[e];
      float w = ew[e];
      acc += w * hw2[(size_t)s * NCLASS + lane];
    }
  }
  // wave-wide max over active lanes
  float v = act ? acc : -INFINITY;
#pragma unroll
  for (int o = 32; o > 0; o >>= 1) v = fmaxf(v, __shfl_xor(v, o));
  float m  = v;
  float ex = act ? expf(acc - m) : 0.f;
  float s  = ex;
#pragma unroll
  for (int o = 32; o > 0; o >>= 1) s += __shfl_xor(s, o);
  float ls = logf(s);
  if (act) out[(size_t)i * NCLASS + lane] = acc - m - ls;
}

// ---------------- launcher ----------------

extern "C" void kernel_launch(void* const* d_in, const int* in_sizes, int n_in,
                              void* d_out, int out_size, void* d_ws, size_t ws_size,
                              hipStream_t stream) {
  const float* x        = (const float*)d_in[0];
  const int*   edge_src = (const int*)  d_in[1];
  const int*   edge_dst = (const int*)  d_in[2];
  const float* edge_w   = (const float*)d_in[3];
  const float* W1       = (const float*)d_in[4];
  const float* b1       = (const float*)d_in[5];
  const float* W2       = (const float*)d_in[6];
  const float* b2       = (const float*)d_in[7];
  float* out = (float*)d_out;

  char* ws = (char*)d_ws;
  size_t off = 0;
  float* xw1 = (float*)(ws + off); off += (size_t)N_NODES * NHID * 4;     // 10.24 MB
  float* h   = (float*)(ws + off); off += (size_t)N_NODES * NHID * 4;     // 10.24 MB
  float* hw2 = (float*)(ws + off); off += (size_t)N_NODES * NCLASS * 4;   // 1.6 MB
  int*   deg = (int*)  (ws + off); off += (size_t)N_NODES * 4;
  int*   rp  = (int*)  (ws + off); off += (size_t)(N_NODES + 4) * 4;
  int*   nxt = (int*)  (ws + off); off += (size_t)N_NODES * 4;
  int*   esrc= (int*)  (ws + off); off += (size_t)N_EDGES * 4;
  float* ew  = (float*)(ws + off); off += (size_t)N_EDGES * 4;

  hipMemsetAsync(deg, 0, (size_t)N_NODES * 4, stream);

  const int EB = (N_EDGES + 255) / 256;
  count_k  <<<EB, 256, 0, stream>>>(edge_dst, deg);
  scan_k   <<<1, 256, 0, stream>>>(deg, rp, nxt);
  scatter_k<<<EB, 256, 0, stream>>>(edge_src, edge_dst, edge_w, nxt, esrc, ew);

  dim3 g1((N_NODES + 63) / 64, NHID / 64);
  gemm1_k<<<g1, 256, 0, stream>>>(x, W1, xw1);

  spmm1_k<<<N_NODES, 256, 0, stream>>>(rp, esrc, ew, xw1, b1, h);

  gemm2_k<<<N_NODES / 16, 256, 0, stream>>>(h, W2, hw2);

  spmm2_k<<<N_NODES, 64, 0, stream>>>(rp, esrc, ew, hw2, b2, out);
}

// Round 2
// 171.452 us; speedup vs baseline: 1.3955x; 1.3955x over previous
//
#include <hip/hip_runtime.h>
#include <hip/hip_bf16.h>
#include <math.h>

#define N_NODES 10000
#define MPAD    10048      // 157 * 64
#define N_EDGES 320000
#define NFEAT   512
#define NHID    256
#define NCLASS  40

typedef short  short8  __attribute__((ext_vector_type(8)));
typedef float  floatx4 __attribute__((ext_vector_type(4)));

__device__ __forceinline__ unsigned short f2b(float f) {
  __hip_bfloat16 h = __float2bfloat16(f);
  unsigned short u; __builtin_memcpy(&u, &h, 2); return u;
}
__device__ __forceinline__ float b2f(unsigned short u) {
  return __uint_as_float(((unsigned)u) << 16);
}

// ---------------- CSR build (bucket edges by dst) ----------------

__global__ __launch_bounds__(256) void count_k(const int* __restrict__ dst,
                                               int* __restrict__ deg) {
  int e = blockIdx.x * 256 + threadIdx.x;
  if (e < N_EDGES) atomicAdd(&deg[dst[e]], 1);
}

__global__ __launch_bounds__(256) void scan_k(const int* __restrict__ deg,
                                              int* __restrict__ rp,
                                              int* __restrict__ nxt) {
  __shared__ int part[256];
  int t = threadIdx.x;
  const int CH = 40;                    // 256*40 = 10240 >= 10000
  int lo = t * CH, hi = lo + CH;
  if (lo > N_NODES) lo = N_NODES;
  if (hi > N_NODES) hi = N_NODES;
  int s = 0;
  for (int j = lo; j < hi; j++) s += deg[j];
  part[t] = s;
  __syncthreads();
  if (t == 0) {
    int r = 0;
    for (int j = 0; j < 256; j++) { int v = part[j]; part[j] = r; r += v; }
  }
  __syncthreads();
  int r = part[t];
  for (int j = lo; j < hi; j++) { rp[j] = r; nxt[j] = r; r += deg[j]; }
  if (t == 255) rp[N_NODES] = r;        // = N_EDGES
}

__global__ __launch_bounds__(256) void scatter_k(const int* __restrict__ src,
                                                 const int* __restrict__ dst,
                                                 const float* __restrict__ w,
                                                 int* __restrict__ nxt,
                                                 int2* __restrict__ epk) {
  int e = blockIdx.x * 256 + threadIdx.x;
  if (e < N_EDGES) {
    int d = dst[e];
    int p = atomicAdd(&nxt[d], 1);
    int2 pk; pk.x = src[e]; pk.y = __float_as_int(w[e]);
    epk[p] = pk;
  }
}

// ---------------- prep: x -> bf16 (padded rows zeroed), W1 -> bf16 transposed ----------------

__global__ __launch_bounds__(256) void prep_k(const float* __restrict__ x,
                                              const float* __restrict__ W1,
                                              unsigned short* __restrict__ xb,
                                              unsigned short* __restrict__ w1t) {
  int tid = blockIdx.x * 256 + threadIdx.x;
  const int nx4 = MPAD * NFEAT / 4;
  if (tid < nx4) {
    int i = tid * 4;
    int row = i / NFEAT;
    float4 v = make_float4(0.f, 0.f, 0.f, 0.f);
    if (row < N_NODES) v = *(const float4*)&x[i];
    ushort4 o;
    o.x = f2b(v.x); o.y = f2b(v.y); o.z = f2b(v.z); o.w = f2b(v.w);
    *(ushort4*)&xb[i] = o;
  } else {
    int j = tid - nx4;
    if (j < NFEAT * NHID) {
      int k = j / NHID, n = j % NHID;            // coalesced read of W1
      w1t[n * NFEAT + k] = f2b(W1[j]);           // transposed bf16 write
    }
  }
}

// ---------------- GEMM1: xw1b = bf16( xb @ W1 )  via MFMA 16x16x32 ----------------
// 64x64 tile, BK=32, 256 threads (4 waves, 2x2 wave grid, 32x32 per wave).
// LDS layout: [row 0..63][four 16B k-slots], slot XOR-swizzled by (row&3).

__global__ __launch_bounds__(256) void gemm1_k(const unsigned short* __restrict__ xb,
                                               const unsigned short* __restrict__ w1t,
                                               unsigned short* __restrict__ xw1b) {
  __shared__ short8 As[64 * 4];   // 4 KB
  __shared__ short8 Bs[64 * 4];   // 4 KB

  const int t  = threadIdx.x;
  const int bm = blockIdx.x * 64;
  const int bn = blockIdx.y * 64;
  const int l  = t & 63;
  const int w  = t >> 6;
  const int wr = w >> 1, wc = w & 1;

  const int srow  = t >> 2;       // staging: row 0..63
  const int sslot = t & 3;        // staging: 16B k-slot 0..3

  const floatx4 zero = {0.f, 0.f, 0.f, 0.f};
  floatx4 acc[2][2];
  acc[0][0] = zero; acc[0][1] = zero; acc[1][0] = zero; acc[1][1] = zero;

  const int q = l >> 4;           // frag k-slot

  for (int k0 = 0; k0 < NFEAT; k0 += 32) {
    short8 av = *(const short8*)&xb [(size_t)(bm + srow) * NFEAT + k0 + sslot * 8];
    short8 bv = *(const short8*)&w1t[(size_t)(bn + srow) * NFEAT + k0 + sslot * 8];
    __syncthreads();              // previous iter's reads done before overwrite
    As[srow * 4 + (sslot ^ (srow & 3))] = av;
    Bs[srow * 4 + (sslot ^ (srow & 3))] = bv;
    __syncthreads();

    short8 af[2], bfr[2];
#pragma unroll
    for (int mi = 0; mi < 2; mi++) {
      int ar = wr * 32 + mi * 16 + (l & 15);
      af[mi] = As[ar * 4 + (q ^ (ar & 3))];
    }
#pragma unroll
    for (int ni = 0; ni < 2; ni++) {
      int bc = wc * 32 + ni * 16 + (l & 15);
      bfr[ni] = Bs[bc * 4 + (q ^ (bc & 3))];
    }
#pragma unroll
    for (int mi = 0; mi < 2; mi++)
#pragma unroll
      for (int ni = 0; ni < 2; ni++)
        acc[mi][ni] = __builtin_amdgcn_mfma_f32_16x16x32_bf16(af[mi], bfr[ni], acc[mi][ni], 0, 0, 0);
  }

  // D layout: col = lane&15, row = (lane>>4)*4 + reg
#pragma unroll
  for (int mi = 0; mi < 2; mi++)
#pragma unroll
    for (int ni = 0; ni < 2; ni++) {
      int row = bm + wr * 32 + mi * 16 + (l >> 4) * 4;
      int col = bn + wc * 32 + ni * 16 + (l & 15);
#pragma unroll
      for (int r = 0; r < 4; r++)
        xw1b[(size_t)(row + r) * NHID + col] = f2b(acc[mi][ni][r]);
    }
}

// ---------------- SpMM1: h = bf16(relu(A_csr * xw1 + b1)) ----------------
// 4 feature-slices of 64; slice tied to XCD pair via blockIdx swizzle so each
// XCD's gathers touch only a 1.25 MB slice of xw1b (L2-resident).

__global__ __launch_bounds__(64) void spmm1_k(const int* __restrict__ rp,
                                              const int2* __restrict__ epk,
                                              const unsigned short* __restrict__ xw1b,
                                              const float* __restrict__ b1,
                                              unsigned short* __restrict__ h) {
  int bid   = blockIdx.x;
  int xcd   = bid & 7;
  int slice = xcd >> 1;
  int node  = (bid >> 3) + (xcd & 1) * 5000;
  int lane  = threadIdx.x;
  int f0    = slice * 64 + lane;

  int e0 = rp[node], e1 = rp[node + 1];
  float acc = 0.f;
  int e = e0;
  for (; e + 4 <= e1; e += 4) {
    int2 p0 = epk[e], p1 = epk[e + 1], p2 = epk[e + 2], p3 = epk[e + 3];
    float v0 = b2f(xw1b[(size_t)p0.x * NHID + f0]);
    float v1 = b2f(xw1b[(size_t)p1.x * NHID + f0]);
    float v2 = b2f(xw1b[(size_t)p2.x * NHID + f0]);
    float v3 = b2f(xw1b[(size_t)p3.x * NHID + f0]);
    acc = fmaf(__int_as_float(p0.y), v0, acc);
    acc = fmaf(__int_as_float(p1.y), v1, acc);
    acc = fmaf(__int_as_float(p2.y), v2, acc);
    acc = fmaf(__int_as_float(p3.y), v3, acc);
  }
  for (; e < e1; e++) {
    int2 p = epk[e];
    acc = fmaf(__int_as_float(p.y), b2f(xw1b[(size_t)p.x * NHID + f0]), acc);
  }
  acc += b1[f0];
  h[(size_t)node * NHID + f0] = f2b(fmaxf(acc, 0.f));
}

// ---------------- GEMM2: hw2 = h @ W2  (10000x256 @ 256x40, h bf16) ----------------

__global__ __launch_bounds__(256) void gemm2_k(const unsigned short* __restrict__ h,
                                               const float* __restrict__ W2,
                                               float* __restrict__ hw2) {
  int t  = threadIdx.x;
  int c  = t & 63;
  int ty = t >> 6;
  int r0 = blockIdx.x * 16 + ty * 4;
  bool act = (c < NCLASS);
  float acc0 = 0.f, acc1 = 0.f, acc2 = 0.f, acc3 = 0.f;
  const unsigned short* h0 = h + (size_t)r0 * NHID;
  for (int k = 0; k < NHID; k++) {
    float w = act ? W2[k * NCLASS + c] : 0.f;
    float x0 = b2f(h0[k]);
    float x1 = b2f(h0[NHID + k]);
    float x2 = b2f(h0[2 * NHID + k]);
    float x3 = b2f(h0[3 * NHID + k]);
    acc0 = fmaf(x0, w, acc0); acc1 = fmaf(x1, w, acc1);
    acc2 = fmaf(x2, w, acc2); acc3 = fmaf(x3, w, acc3);
  }
  if (act) {
    hw2[(size_t)(r0 + 0) * NCLASS + c] = acc0;
    hw2[(size_t)(r0 + 1) * NCLASS + c] = acc1;
    hw2[(size_t)(r0 + 2) * NCLASS + c] = acc2;
    hw2[(size_t)(r0 + 3) * NCLASS + c] = acc3;
  }
}

// ---------------- SpMM2 + b2 + log_softmax -> out ----------------

__global__ __launch_bounds__(64) void spmm2_k(const int* __restrict__ rp,
                                              const int2* __restrict__ epk,
                                              const float* __restrict__ hw2,
                                              const float* __restrict__ b2,
                                              float* __restrict__ out) {
  int i    = blockIdx.x;
  int lane = threadIdx.x;
  bool act = (lane < NCLASS);
  int e0 = rp[i], e1 = rp[i + 1];
  float acc = act ? b2[lane] : 0.f;
  if (act) {
    for (int e = e0; e < e1; e++) {
      int2 p = epk[e];
      acc = fmaf(__int_as_float(p.y), hw2[(size_t)p.x * NCLASS + lane], acc);
    }
  }
  float v = act ? acc : -INFINITY;
#pragma unroll
  for (int o = 32; o > 0; o >>= 1) v = fmaxf(v, __shfl_xor(v, o));
  float m  = v;
  float ex = act ? expf(acc - m) : 0.f;
  float s  = ex;
#pragma unroll
  for (int o = 32; o > 0; o >>= 1) s += __shfl_xor(s, o);
  float ls = logf(s);
  if (act) out[(size_t)i * NCLASS + lane] = acc - m - ls;
}

// ---------------- launcher ----------------

static inline size_t align256(size_t v) { return (v + 255) & ~(size_t)255; }

extern "C" void kernel_launch(void* const* d_in, const int* in_sizes, int n_in,
                              void* d_out, int out_size, void* d_ws, size_t ws_size,
                              hipStream_t stream) {
  const float* x        = (const float*)d_in[0];
  const int*   edge_src = (const int*)  d_in[1];
  const int*   edge_dst = (const int*)  d_in[2];
  const float* edge_w   = (const float*)d_in[3];
  const float* W1       = (const float*)d_in[4];
  const float* b1       = (const float*)d_in[5];
  const float* W2       = (const float*)d_in[6];
  const float* b2       = (const float*)d_in[7];
  float* out = (float*)d_out;

  char* ws = (char*)d_ws;
  size_t off = 0;
  unsigned short* xb   = (unsigned short*)(ws + off); off = align256(off + (size_t)MPAD * NFEAT * 2);   // 10.29 MB
  unsigned short* w1t  = (unsigned short*)(ws + off); off = align256(off + (size_t)NFEAT * NHID * 2);   // 0.26 MB
  unsigned short* xw1b = (unsigned short*)(ws + off); off = align256(off + (size_t)MPAD * NHID * 2);    // 5.14 MB
  unsigned short* h    = (unsigned short*)(ws + off); off = align256(off + (size_t)N_NODES * NHID * 2); // 5.12 MB
  float* hw2 = (float*)(ws + off); off = align256(off + (size_t)N_NODES * NCLASS * 4);                  // 1.6 MB
  int*   deg = (int*)  (ws + off); off = align256(off + (size_t)N_NODES * 4);
  int*   rp  = (int*)  (ws + off); off = align256(off + (size_t)(N_NODES + 4) * 4);
  int*   nxt = (int*)  (ws + off); off = align256(off + (size_t)N_NODES * 4);
  int2*  epk = (int2*) (ws + off); off = align256(off + (size_t)N_EDGES * 8);                           // 2.56 MB

  hipMemsetAsync(deg, 0, (size_t)N_NODES * 4, stream);

  const int EB = (N_EDGES + 255) / 256;
  count_k  <<<EB, 256, 0, stream>>>(edge_dst, deg);
  scan_k   <<<1, 256, 0, stream>>>(deg, rp, nxt);
  scatter_k<<<EB, 256, 0, stream>>>(edge_src, edge_dst, edge_w, nxt, epk);

  const int PREP_ITEMS = MPAD * NFEAT / 4 + NFEAT * NHID;
  prep_k<<<(PREP_ITEMS + 255) / 256, 256, 0, stream>>>(x, W1, xb, w1t);

  dim3 g1(MPAD / 64, NHID / 64);
  gemm1_k<<<g1, 256, 0, stream>>>(xb, w1t, xw1b);

  spmm1_k<<<40000, 64, 0, stream>>>(rp, epk, xw1b, b1, h);

  gemm2_k<<<N_NODES / 16, 256, 0, stream>>>(h, W2, hw2);

  spmm2_k<<<N_NODES, 64, 0, stream>>>(rp, epk, hw2, b2, out);
}

// Round 3
// 166.774 us; speedup vs baseline: 1.4346x; 1.0281x over previous
//
#include <hip/hip_runtime.h>
#include <hip/hip_bf16.h>
#include <math.h>

#define N_NODES 10000
#define MPAD    10048      // 157 * 64
#define N_EDGES 320000
#define NFEAT   512
#define NHID    256
#define NCLASS  40

typedef short  short8  __attribute__((ext_vector_type(8)));
typedef float  floatx4 __attribute__((ext_vector_type(4)));

__device__ __forceinline__ unsigned short f2b(float f) {
  __hip_bfloat16 h = __float2bfloat16(f);
  unsigned short u; __builtin_memcpy(&u, &h, 2); return u;
}
__device__ __forceinline__ float b2f(unsigned short u) {
  return __uint_as_float(((unsigned)u) << 16);
}

// ---------------- prep: x -> bf16 (padded rows zeroed), W1 -> bf16 transposed,
//                  deg -> 0 (replaces the pathological hipMemsetAsync fill) ----

__global__ __launch_bounds__(256) void prep_k(const float* __restrict__ x,
                                              const float* __restrict__ W1,
                                              unsigned short* __restrict__ xb,
                                              unsigned short* __restrict__ w1t,
                                              int* __restrict__ deg) {
  int tid = blockIdx.x * 256 + threadIdx.x;
  if (tid < N_NODES) deg[tid] = 0;
  const int nx4 = MPAD * NFEAT / 4;
  if (tid < nx4) {
    int i = tid * 4;
    int row = i / NFEAT;
    float4 v = make_float4(0.f, 0.f, 0.f, 0.f);
    if (row < N_NODES) v = *(const float4*)&x[i];
    ushort4 o;
    o.x = f2b(v.x); o.y = f2b(v.y); o.z = f2b(v.z); o.w = f2b(v.w);
    *(ushort4*)&xb[i] = o;
  } else {
    int j = tid - nx4;
    if (j < NFEAT * NHID) {
      int k = j / NHID, n = j % NHID;            // coalesced read of W1
      w1t[n * NFEAT + k] = f2b(W1[j]);           // transposed bf16 write
    }
  }
}

// ---------------- CSR build (bucket edges by dst) ----------------

__global__ __launch_bounds__(256) void count_k(const int* __restrict__ dst,
                                               int* __restrict__ deg) {
  int e = blockIdx.x * 256 + threadIdx.x;
  if (e < N_EDGES) atomicAdd(&deg[dst[e]], 1);
}

__global__ __launch_bounds__(256) void scan_k(const int* __restrict__ deg,
                                              int* __restrict__ rp,
                                              int* __restrict__ nxt) {
  __shared__ int part[256];
  int t = threadIdx.x;
  const int CH = 40;                    // 256*40 = 10240 >= 10000
  int lo = t * CH, hi = lo + CH;
  if (lo > N_NODES) lo = N_NODES;
  if (hi > N_NODES) hi = N_NODES;
  int s = 0;
  for (int j = lo; j < hi; j++) s += deg[j];
  part[t] = s;
  __syncthreads();
  if (t == 0) {
    int r = 0;
    for (int j = 0; j < 256; j++) { int v = part[j]; part[j] = r; r += v; }
  }
  __syncthreads();
  int r = part[t];
  for (int j = lo; j < hi; j++) { rp[j] = r; nxt[j] = r; r += deg[j]; }
  if (t == 255) rp[N_NODES] = r;        // = N_EDGES
}

__global__ __launch_bounds__(256) void scatter_k(const int* __restrict__ src,
                                                 const int* __restrict__ dst,
                                                 const float* __restrict__ w,
                                                 int* __restrict__ nxt,
                                                 int2* __restrict__ epk) {
  int e = blockIdx.x * 256 + threadIdx.x;
  if (e < N_EDGES) {
    int d = dst[e];
    int p = atomicAdd(&nxt[d], 1);
    int2 pk; pk.x = src[e]; pk.y = __float_as_int(w[e]);
    epk[p] = pk;
  }
}

// ---------------- GEMM1: xw1b = bf16( xb @ W1 )  via MFMA 16x16x32 ----------------
// 64x64 tile, BK=32, 256 threads (4 waves, 2x2 wave grid, 32x32 per wave).
// LDS layout: [row 0..63][four 16B k-slots], slot XOR-swizzled by (row&3).

__global__ __launch_bounds__(256) void gemm1_k(const unsigned short* __restrict__ xb,
                                               const unsigned short* __restrict__ w1t,
                                               unsigned short* __restrict__ xw1b) {
  __shared__ short8 As[64 * 4];   // 4 KB
  __shared__ short8 Bs[64 * 4];   // 4 KB

  const int t  = threadIdx.x;
  const int bm = blockIdx.x * 64;
  const int bn = blockIdx.y * 64;
  const int l  = t & 63;
  const int w  = t >> 6;
  const int wr = w >> 1, wc = w & 1;

  const int srow  = t >> 2;       // staging: row 0..63
  const int sslot = t & 3;        // staging: 16B k-slot 0..3

  const floatx4 zero = {0.f, 0.f, 0.f, 0.f};
  floatx4 acc[2][2];
  acc[0][0] = zero; acc[0][1] = zero; acc[1][0] = zero; acc[1][1] = zero;

  const int q = l >> 4;           // frag k-slot

  for (int k0 = 0; k0 < NFEAT; k0 += 32) {
    short8 av = *(const short8*)&xb [(size_t)(bm + srow) * NFEAT + k0 + sslot * 8];
    short8 bv = *(const short8*)&w1t[(size_t)(bn + srow) * NFEAT + k0 + sslot * 8];
    __syncthreads();              // previous iter's reads done before overwrite
    As[srow * 4 + (sslot ^ (srow & 3))] = av;
    Bs[srow * 4 + (sslot ^ (srow & 3))] = bv;
    __syncthreads();

    short8 af[2], bfr[2];
#pragma unroll
    for (int mi = 0; mi < 2; mi++) {
      int ar = wr * 32 + mi * 16 + (l & 15);
      af[mi] = As[ar * 4 + (q ^ (ar & 3))];
    }
#pragma unroll
    for (int ni = 0; ni < 2; ni++) {
      int bc = wc * 32 + ni * 16 + (l & 15);
      bfr[ni] = Bs[bc * 4 + (q ^ (bc & 3))];
    }
#pragma unroll
    for (int mi = 0; mi < 2; mi++)
#pragma unroll
      for (int ni = 0; ni < 2; ni++)
        acc[mi][ni] = __builtin_amdgcn_mfma_f32_16x16x32_bf16(af[mi], bfr[ni], acc[mi][ni], 0, 0, 0);
  }

  // D layout: col = lane&15, row = (lane>>4)*4 + reg
#pragma unroll
  for (int mi = 0; mi < 2; mi++)
#pragma unroll
    for (int ni = 0; ni < 2; ni++) {
      int row = bm + wr * 32 + mi * 16 + (l >> 4) * 4;
      int col = bn + wc * 32 + ni * 16 + (l & 15);
#pragma unroll
      for (int r = 0; r < 4; r++)
        xw1b[(size_t)(row + r) * NHID + col] = f2b(acc[mi][ni][r]);
    }
}

// ---------------- SpMM1: h = bf16(relu(A_csr * xw1 + b1)) ----------------
// 4 feature-slices of 64; slice tied to XCD pair via blockIdx swizzle so each
// XCD's gathers touch only a 1.25 MB slice of xw1b (L2-resident).

__global__ __launch_bounds__(64) void spmm1_k(const int* __restrict__ rp,
                                              const int2* __restrict__ epk,
                                              const unsigned short* __restrict__ xw1b,
                                              const float* __restrict__ b1,
                                              unsigned short* __restrict__ h) {
  int bid   = blockIdx.x;
  int xcd   = bid & 7;
  int slice = xcd >> 1;
  int node  = (bid >> 3) + (xcd & 1) * 5000;
  int lane  = threadIdx.x;
  int f0    = slice * 64 + lane;

  int e0 = rp[node], e1 = rp[node + 1];
  float acc = 0.f;
  int e = e0;
  for (; e + 4 <= e1; e += 4) {
    int2 p0 = epk[e], p1 = epk[e + 1], p2 = epk[e + 2], p3 = epk[e + 3];
    float v0 = b2f(xw1b[(size_t)p0.x * NHID + f0]);
    float v1 = b2f(xw1b[(size_t)p1.x * NHID + f0]);
    float v2 = b2f(xw1b[(size_t)p2.x * NHID + f0]);
    float v3 = b2f(xw1b[(size_t)p3.x * NHID + f0]);
    acc = fmaf(__int_as_float(p0.y), v0, acc);
    acc = fmaf(__int_as_float(p1.y), v1, acc);
    acc = fmaf(__int_as_float(p2.y), v2, acc);
    acc = fmaf(__int_as_float(p3.y), v3, acc);
  }
  for (; e < e1; e++) {
    int2 p = epk[e];
    acc = fmaf(__int_as_float(p.y), b2f(xw1b[(size_t)p.x * NHID + f0]), acc);
  }
  acc += b1[f0];
  h[(size_t)node * NHID + f0] = f2b(fmaxf(acc, 0.f));
}

// ---------------- GEMM2: hw2 = h @ W2  (10000x256 @ 256x40, h bf16) ----------------

__global__ __launch_bounds__(256) void gemm2_k(const unsigned short* __restrict__ h,
                                               const float* __restrict__ W2,
                                               float* __restrict__ hw2) {
  int t  = threadIdx.x;
  int c  = t & 63;
  int ty = t >> 6;
  int r0 = blockIdx.x * 16 + ty * 4;
  bool act = (c < NCLASS);
  float acc0 = 0.f, acc1 = 0.f, acc2 = 0.f, acc3 = 0.f;
  const unsigned short* h0 = h + (size_t)r0 * NHID;
  for (int k = 0; k < NHID; k++) {
    float w = act ? W2[k * NCLASS + c] : 0.f;
    float x0 = b2f(h0[k]);
    float x1 = b2f(h0[NHID + k]);
    float x2 = b2f(h0[2 * NHID + k]);
    float x3 = b2f(h0[3 * NHID + k]);
    acc0 = fmaf(x0, w, acc0); acc1 = fmaf(x1, w, acc1);
    acc2 = fmaf(x2, w, acc2); acc3 = fmaf(x3, w, acc3);
  }
  if (act) {
    hw2[(size_t)(r0 + 0) * NCLASS + c] = acc0;
    hw2[(size_t)(r0 + 1) * NCLASS + c] = acc1;
    hw2[(size_t)(r0 + 2) * NCLASS + c] = acc2;
    hw2[(size_t)(r0 + 3) * NCLASS + c] = acc3;
  }
}

// ---------------- SpMM2 + b2 + log_softmax -> out ----------------

__global__ __launch_bounds__(64) void spmm2_k(const int* __restrict__ rp,
                                              const int2* __restrict__ epk,
                                              const float* __restrict__ hw2,
                                              const float* __restrict__ b2,
                                              float* __restrict__ out) {
  int i    = blockIdx.x;
  int lane = threadIdx.x;
  bool act = (lane < NCLASS);
  int e0 = rp[i], e1 = rp[i + 1];
  float acc = act ? b2[lane] : 0.f;
  if (act) {
    for (int e = e0; e < e1; e++) {
      int2 p = epk[e];
      acc = fmaf(__int_as_float(p.y), hw2[(size_t)p.x * NCLASS + lane], acc);
    }
  }
  float v = act ? acc : -INFINITY;
#pragma unroll
  for (int o = 32; o > 0; o >>= 1) v = fmaxf(v, __shfl_xor(v, o));
  float m  = v;
  float ex = act ? expf(acc - m) : 0.f;
  float s  = ex;
#pragma unroll
  for (int o = 32; o > 0; o >>= 1) s += __shfl_xor(s, o);
  float ls = logf(s);
  if (act) out[(size_t)i * NCLASS + lane] = acc - m - ls;
}

// ---------------- launcher ----------------

static inline size_t align256(size_t v) { return (v + 255) & ~(size_t)255; }

extern "C" void kernel_launch(void* const* d_in, const int* in_sizes, int n_in,
                              void* d_out, int out_size, void* d_ws, size_t ws_size,
                              hipStream_t stream) {
  const float* x        = (const float*)d_in[0];
  const int*   edge_src = (const int*)  d_in[1];
  const int*   edge_dst = (const int*)  d_in[2];
  const float* edge_w   = (const float*)d_in[3];
  const float* W1       = (const float*)d_in[4];
  const float* b1       = (const float*)d_in[5];
  const float* W2       = (const float*)d_in[6];
  const float* b2       = (const float*)d_in[7];
  float* out = (float*)d_out;

  char* ws = (char*)d_ws;
  size_t off = 0;
  unsigned short* xb   = (unsigned short*)(ws + off); off = align256(off + (size_t)MPAD * NFEAT * 2);   // 10.29 MB
  unsigned short* w1t  = (unsigned short*)(ws + off); off = align256(off + (size_t)NFEAT * NHID * 2);   // 0.26 MB
  unsigned short* xw1b = (unsigned short*)(ws + off); off = align256(off + (size_t)MPAD * NHID * 2);    // 5.14 MB
  unsigned short* h    = (unsigned short*)(ws + off); off = align256(off + (size_t)N_NODES * NHID * 2); // 5.12 MB
  float* hw2 = (float*)(ws + off); off = align256(off + (size_t)N_NODES * NCLASS * 4);                  // 1.6 MB
  int*   deg = (int*)  (ws + off); off = align256(off + (size_t)N_NODES * 4);
  int*   rp  = (int*)  (ws + off); off = align256(off + (size_t)(N_NODES + 4) * 4);
  int*   nxt = (int*)  (ws + off); off = align256(off + (size_t)N_NODES * 4);
  int2*  epk = (int2*) (ws + off); off = align256(off + (size_t)N_EDGES * 8);                           // 2.56 MB

  const int PREP_ITEMS = MPAD * NFEAT / 4 + NFEAT * NHID;
  prep_k<<<(PREP_ITEMS + 255) / 256, 256, 0, stream>>>(x, W1, xb, w1t, deg);

  const int EB = (N_EDGES + 255) / 256;
  count_k  <<<EB, 256, 0, stream>>>(edge_dst, deg);
  scan_k   <<<1, 256, 0, stream>>>(deg, rp, nxt);
  scatter_k<<<EB, 256, 0, stream>>>(edge_src, edge_dst, edge_w, nxt, epk);

  dim3 g1(MPAD / 64, NHID / 64);
  gemm1_k<<<g1, 256, 0, stream>>>(xb, w1t, xw1b);

  spmm1_k<<<40000, 64, 0, stream>>>(rp, epk, xw1b, b1, h);

  gemm2_k<<<N_NODES / 16, 256, 0, stream>>>(h, W2, hw2);

  spmm2_k<<<N_NODES, 64, 0, stream>>>(rp, epk, hw2, b2, out);
}

// Round 5
// 144.270 us; speedup vs baseline: 1.6584x; 1.1560x over previous
//
#include <hip/hip_runtime.h>
#include <hip/hip_bf16.h>
#include <math.h>

#define N_NODES 10000
#define MPAD    10048      // 157 * 64
#define N_EDGES 320000
#define NFEAT   512
#define NHID    256
#define NCLASS  40

typedef short  short8  __attribute__((ext_vector_type(8)));
typedef float  floatx4 __attribute__((ext_vector_type(4)));

__device__ __forceinline__ unsigned short f2b(float f) {
  __hip_bfloat16 h = __float2bfloat16(f);
  unsigned short u; __builtin_memcpy(&u, &h, 2); return u;
}
__device__ __forceinline__ float b2f(unsigned short u) {
  return __uint_as_float(((unsigned)u) << 16);
}

// ---------------- prep: x -> bf16 (padded rows zeroed), W1 -> bf16 transposed,
//                  deg -> 0 ----------------

__global__ __launch_bounds__(256) void prep_k(const float* __restrict__ x,
                                              const float* __restrict__ W1,
                                              unsigned short* __restrict__ xb,
                                              unsigned short* __restrict__ w1t,
                                              int* __restrict__ deg) {
  int tid = blockIdx.x * 256 + threadIdx.x;
  if (tid < N_NODES) deg[tid] = 0;
  const int nx4 = MPAD * NFEAT / 4;
  if (tid < nx4) {
    int i = tid * 4;
    int row = i / NFEAT;
    float4 v = make_float4(0.f, 0.f, 0.f, 0.f);
    if (row < N_NODES) v = *(const float4*)&x[i];
    ushort4 o;
    o.x = f2b(v.x); o.y = f2b(v.y); o.z = f2b(v.z); o.w = f2b(v.w);
    *(ushort4*)&xb[i] = o;
  } else {
    int j = tid - nx4;
    if (j < NFEAT * NHID) {
      int k = j / NHID, n = j % NHID;            // coalesced read of W1
      w1t[n * NFEAT + k] = f2b(W1[j]);           // transposed bf16 write
    }
  }
}

// ---------------- CSR build (bucket edges by dst) ----------------

__global__ __launch_bounds__(256) void count_k(const int* __restrict__ dst,
                                               int* __restrict__ deg) {
  int e = blockIdx.x * 256 + threadIdx.x;
  if (e < N_EDGES) atomicAdd(&deg[dst[e]], 1);
}

// 1024 threads, two-level shfl scan — no serial section.
__global__ __launch_bounds__(1024) void scan_k(const int* __restrict__ deg,
                                               int* __restrict__ rp,
                                               int* __restrict__ nxt) {
  __shared__ int wsum[16];
  int t    = threadIdx.x;
  int lane = t & 63, wv = t >> 6;
  const int CH = 10;                    // 1024*10 = 10240 >= 10000
  int lo = t * CH, hi = lo + CH;
  if (lo > N_NODES) lo = N_NODES;
  if (hi > N_NODES) hi = N_NODES;
  int s = 0;
#pragma unroll
  for (int jj = 0; jj < CH; jj++) {
    int j = lo + jj;
    if (j < hi) s += deg[j];
  }
  // inclusive scan within wave
  int inc = s;
#pragma unroll
  for (int off = 1; off < 64; off <<= 1) {
    int v = __shfl_up(inc, off);
    if (lane >= off) inc += v;
  }
  if (lane == 63) wsum[wv] = inc;
  __syncthreads();
  if (wv == 0) {
    int v = (lane < 16) ? wsum[lane] : 0;
    int vinc = v;
#pragma unroll
    for (int off = 1; off < 16; off <<= 1) {
      int u = __shfl_up(vinc, off);
      if (lane >= off) vinc += u;
    }
    if (lane < 16) wsum[lane] = vinc - v;      // exclusive wave prefix
  }
  __syncthreads();
  int r = wsum[wv] + inc - s;                  // exclusive prefix for this thread
#pragma unroll
  for (int jj = 0; jj < CH; jj++) {
    int j = lo + jj;
    if (j < hi) { rp[j] = r; nxt[j] = r; r += deg[j]; }
  }
  if (hi == N_NODES) rp[N_NODES] = r;          // all clamped threads write same total
}

__global__ __launch_bounds__(256) void scatter_k(const int* __restrict__ src,
                                                 const int* __restrict__ dst,
                                                 const float* __restrict__ w,
                                                 int* __restrict__ nxt,
                                                 int2* __restrict__ epk) {
  int e = blockIdx.x * 256 + threadIdx.x;
  if (e < N_EDGES) {
    int d = dst[e];
    int p = atomicAdd(&nxt[d], 1);
    int2 pk; pk.x = src[e]; pk.y = __float_as_int(w[e]);
    epk[p] = pk;
  }
}

// ---------------- GEMM1: xw1b = bf16( xb @ W1 )  via MFMA 16x16x32 ----------------

__global__ __launch_bounds__(256) void gemm1_k(const unsigned short* __restrict__ xb,
                                               const unsigned short* __restrict__ w1t,
                                               unsigned short* __restrict__ xw1b) {
  __shared__ short8 As[64 * 4];   // 4 KB
  __shared__ short8 Bs[64 * 4];   // 4 KB

  const int t  = threadIdx.x;
  const int bm = blockIdx.x * 64;
  const int bn = blockIdx.y * 64;
  const int l  = t & 63;
  const int w  = t >> 6;
  const int wr = w >> 1, wc = w & 1;

  const int srow  = t >> 2;
  const int sslot = t & 3;

  const floatx4 zero = {0.f, 0.f, 0.f, 0.f};
  floatx4 acc[2][2];
  acc[0][0] = zero; acc[0][1] = zero; acc[1][0] = zero; acc[1][1] = zero;

  const int q = l >> 4;

  for (int k0 = 0; k0 < NFEAT; k0 += 32) {
    short8 av = *(const short8*)&xb [(size_t)(bm + srow) * NFEAT + k0 + sslot * 8];
    short8 bv = *(const short8*)&w1t[(size_t)(bn + srow) * NFEAT + k0 + sslot * 8];
    __syncthreads();
    As[srow * 4 + (sslot ^ (srow & 3))] = av;
    Bs[srow * 4 + (sslot ^ (srow & 3))] = bv;
    __syncthreads();

    short8 af[2], bfr[2];
#pragma unroll
    for (int mi = 0; mi < 2; mi++) {
      int ar = wr * 32 + mi * 16 + (l & 15);
      af[mi] = As[ar * 4 + (q ^ (ar & 3))];
    }
#pragma unroll
    for (int ni = 0; ni < 2; ni++) {
      int bc = wc * 32 + ni * 16 + (l & 15);
      bfr[ni] = Bs[bc * 4 + (q ^ (bc & 3))];
    }
#pragma unroll
    for (int mi = 0; mi < 2; mi++)
#pragma unroll
      for (int ni = 0; ni < 2; ni++)
        acc[mi][ni] = __builtin_amdgcn_mfma_f32_16x16x32_bf16(af[mi], bfr[ni], acc[mi][ni], 0, 0, 0);
  }

#pragma unroll
  for (int mi = 0; mi < 2; mi++)
#pragma unroll
    for (int ni = 0; ni < 2; ni++) {
      int row = bm + wr * 32 + mi * 16 + (l >> 4) * 4;
      int col = bn + wc * 32 + ni * 16 + (l & 15);
#pragma unroll
      for (int r = 0; r < 4; r++)
        xw1b[(size_t)(row + r) * NHID + col] = f2b(acc[mi][ni][r]);
    }
}

// ---------------- SpMM1: h = bf16(relu(A_csr * xw1 + b1)) ----------------
// 10000 blocks x 256 threads. Block = 4 waves = 4 nodes of the SAME feature
// slice; slice tied to XCD pair via blockIdx&7 so each XCD's gathers touch a
// 1.25 MB slice of xw1b (L2-resident). Wave coalesced-loads 64 epk entries,
// shfl-broadcasts, 4 gathers in flight.

__global__ __launch_bounds__(256) void spmm1_k(const int* __restrict__ rp,
                                               const int2* __restrict__ epk,
                                               const unsigned short* __restrict__ xw1b,
                                               const float* __restrict__ b1,
                                               unsigned short* __restrict__ h) {
  int bid   = blockIdx.x;
  int xcd   = bid & 7;
  int slice = xcd >> 1;
  int half  = xcd & 1;
  int wave  = threadIdx.x >> 6;
  int lane  = threadIdx.x & 63;
  int node  = (bid >> 3) * 4 + wave + half * 5000;
  int f0    = slice * 64 + lane;

  int e0 = rp[node], e1 = rp[node + 1];
  float acc = 0.f;
  for (int base = e0; base < e1; base += 64) {
    int cnt = e1 - base; if (cnt > 64) cnt = 64;
    int2 my = make_int2(0, 0);
    if (lane < cnt) my = epk[base + lane];
    int j = 0;
    for (; j + 4 <= cnt; j += 4) {
      int   s0 = __shfl(my.x, j + 0); float w0 = __int_as_float(__shfl(my.y, j + 0));
      int   s1 = __shfl(my.x, j + 1); float w1 = __int_as_float(__shfl(my.y, j + 1));
      int   s2 = __shfl(my.x, j + 2); float w2 = __int_as_float(__shfl(my.y, j + 2));
      int   s3 = __shfl(my.x, j + 3); float w3 = __int_as_float(__shfl(my.y, j + 3));
      float v0 = b2f(xw1b[(size_t)s0 * NHID + f0]);
      float v1 = b2f(xw1b[(size_t)s1 * NHID + f0]);
      float v2 = b2f(xw1b[(size_t)s2 * NHID + f0]);
      float v3 = b2f(xw1b[(size_t)s3 * NHID + f0]);
      acc = fmaf(w0, v0, acc);
      acc = fmaf(w1, v1, acc);
      acc = fmaf(w2, v2, acc);
      acc = fmaf(w3, v3, acc);
    }
    for (; j < cnt; j++) {
      int   sj = __shfl(my.x, j);
      float wj = __int_as_float(__shfl(my.y, j));
      acc = fmaf(wj, b2f(xw1b[(size_t)sj * NHID + f0]), acc);
    }
  }
  acc += b1[f0];
  h[(size_t)node * NHID + f0] = f2b(fmaxf(acc, 0.f));
}

// ---------------- GEMM2: hw2 = h @ W2  (10000x256 @ 256x40, h bf16) ----------------

__global__ __launch_bounds__(256) void gemm2_k(const unsigned short* __restrict__ h,
                                               const float* __restrict__ W2,
                                               float* __restrict__ hw2) {
  int t  = threadIdx.x;
  int c  = t & 63;
  int ty = t >> 6;
  int r0 = blockIdx.x * 16 + ty * 4;
  bool act = (c < NCLASS);
  float acc0 = 0.f, acc1 = 0.f, acc2 = 0.f, acc3 = 0.f;
  const unsigned short* h0 = h + (size_t)r0 * NHID;
  for (int k = 0; k < NHID; k += 8) {
    short8 x0 = *(const short8*)&h0[k];
    short8 x1 = *(const short8*)&h0[NHID + k];
    short8 x2 = *(const short8*)&h0[2 * NHID + k];
    short8 x3 = *(const short8*)&h0[3 * NHID + k];
#pragma unroll
    for (int u = 0; u < 8; u++) {
      float w = act ? W2[(k + u) * NCLASS + c] : 0.f;
      acc0 = fmaf(b2f((unsigned short)x0[u]), w, acc0);
      acc1 = fmaf(b2f((unsigned short)x1[u]), w, acc1);
      acc2 = fmaf(b2f((unsigned short)x2[u]), w, acc2);
      acc3 = fmaf(b2f((unsigned short)x3[u]), w, acc3);
    }
  }
  if (act) {
    hw2[(size_t)(r0 + 0) * NCLASS + c] = acc0;
    hw2[(size_t)(r0 + 1) * NCLASS + c] = acc1;
    hw2[(size_t)(r0 + 2) * NCLASS + c] = acc2;
    hw2[(size_t)(r0 + 3) * NCLASS + c] = acc3;
  }
}

// ---------------- SpMM2 + b2 + log_softmax -> out ----------------

__global__ __launch_bounds__(64) void spmm2_k(const int* __restrict__ rp,
                                              const int2* __restrict__ epk,
                                              const float* __restrict__ hw2,
                                              const float* __restrict__ b2,
                                              float* __restrict__ out) {
  int i    = blockIdx.x;
  int lane = threadIdx.x;
  bool act = (lane < NCLASS);
  int e0 = rp[i], e1 = rp[i + 1];
  float acc = act ? b2[lane] : 0.f;
  for (int base = e0; base < e1; base += 64) {
    int cnt = e1 - base; if (cnt > 64) cnt = 64;
    int2 my = make_int2(0, 0);
    if (lane < cnt) my = epk[base + lane];
    int j = 0;
    for (; j + 4 <= cnt; j += 4) {
      int   s0 = __shfl(my.x, j + 0); float w0 = __int_as_float(__shfl(my.y, j + 0));
      int   s1 = __shfl(my.x, j + 1); float w1 = __int_as_float(__shfl(my.y, j + 1));
      int   s2 = __shfl(my.x, j + 2); float w2 = __int_as_float(__shfl(my.y, j + 2));
      int   s3 = __shfl(my.x, j + 3); float w3 = __int_as_float(__shfl(my.y, j + 3));
      if (act) {
        float v0 = hw2[(size_t)s0 * NCLASS + lane];
        float v1 = hw2[(size_t)s1 * NCLASS + lane];
        float v2 = hw2[(size_t)s2 * NCLASS + lane];
        float v3 = hw2[(size_t)s3 * NCLASS + lane];
        acc = fmaf(w0, v0, acc);
        acc = fmaf(w1, v1, acc);
        acc = fmaf(w2, v2, acc);
        acc = fmaf(w3, v3, acc);
      }
    }
    for (; j < cnt; j++) {
      int   sj = __shfl(my.x, j);
      float wj = __int_as_float(__shfl(my.y, j));
      if (act) acc = fmaf(wj, hw2[(size_t)sj * NCLASS + lane], acc);
    }
  }
  float v = act ? acc : -INFINITY;
#pragma unroll
  for (int o = 32; o > 0; o >>= 1) v = fmaxf(v, __shfl_xor(v, o));
  float m  = v;
  float ex = act ? expf(acc - m) : 0.f;
  float s  = ex;
#pragma unroll
  for (int o = 32; o > 0; o >>= 1) s += __shfl_xor(s, o);
  float ls = logf(s);
  if (act) out[(size_t)i * NCLASS + lane] = acc - m - ls;
}

// ---------------- launcher ----------------

static inline size_t align256(size_t v) { return (v + 255) & ~(size_t)255; }

extern "C" void kernel_launch(void* const* d_in, const int* in_sizes, int n_in,
                              void* d_out, int out_size, void* d_ws, size_t ws_size,
                              hipStream_t stream) {
  const float* x        = (const float*)d_in[0];
  const int*   edge_src = (const int*)  d_in[1];
  const int*   edge_dst = (const int*)  d_in[2];
  const float* edge_w   = (const float*)d_in[3];
  const float* W1       = (const float*)d_in[4];
  const float* b1       = (const float*)d_in[5];
  const float* W2       = (const float*)d_in[6];
  const float* b2       = (const float*)d_in[7];
  float* out = (float*)d_out;

  char* ws = (char*)d_ws;
  size_t off = 0;
  unsigned short* xb   = (unsigned short*)(ws + off); off = align256(off + (size_t)MPAD * NFEAT * 2);
  unsigned short* w1t  = (unsigned short*)(ws + off); off = align256(off + (size_t)NFEAT * NHID * 2);
  unsigned short* xw1b = (unsigned short*)(ws + off); off = align256(off + (size_t)MPAD * NHID * 2);
  unsigned short* h    = (unsigned short*)(ws + off); off = align256(off + (size_t)N_NODES * NHID * 2);
  float* hw2 = (float*)(ws + off); off = align256(off + (size_t)N_NODES * NCLASS * 4);
  int*   deg = (int*)  (ws + off); off = align256(off + (size_t)N_NODES * 4);
  int*   rp  = (int*)  (ws + off); off = align256(off + (size_t)(N_NODES + 4) * 4);
  int*   nxt = (int*)  (ws + off); off = align256(off + (size_t)N_NODES * 4);
  int2*  epk = (int2*) (ws + off); off = align256(off + (size_t)N_EDGES * 8);

  const int PREP_ITEMS = MPAD * NFEAT / 4 + NFEAT * NHID;
  prep_k<<<(PREP_ITEMS + 255) / 256, 256, 0, stream>>>(x, W1, xb, w1t, deg);

  const int EB = (N_EDGES + 255) / 256;
  count_k  <<<EB, 256, 0, stream>>>(edge_dst, deg);
  scan_k   <<<1, 1024, 0, stream>>>(deg, rp, nxt);
  scatter_k<<<EB, 256, 0, stream>>>(edge_src, edge_dst, edge_w, nxt, epk);

  dim3 g1(MPAD / 64, NHID / 64);
  gemm1_k<<<g1, 256, 0, stream>>>(xb, w1t, xw1b);

  spmm1_k<<<10000, 256, 0, stream>>>(rp, epk, xw1b, b1, h);

  gemm2_k<<<N_NODES / 16, 256, 0, stream>>>(h, W2, hw2);

  spmm2_k<<<N_NODES, 64, 0, stream>>>(rp, epk, hw2, b2, out);
}

// Round 6
// 127.317 us; speedup vs baseline: 1.8792x; 1.1332x over previous
//
#include <hip/hip_runtime.h>
#include <hip/hip_bf16.h>
#include <math.h>

#define N_NODES 10000
#define MPAD    10112      // 79 * 128
#define N_EDGES 320000
#define NFEAT   512
#define NHID    256
#define NCLASS  40
#define EB      ((N_EDGES + 255) / 256)   // 1250
#define G1X     (MPAD / 128)              // 79
#define G1Y     (NHID / 64)               // 4

typedef short  short8  __attribute__((ext_vector_type(8)));
typedef float  floatx4 __attribute__((ext_vector_type(4)));

__device__ __forceinline__ unsigned short f2b(float f) {
  __hip_bfloat16 h = __float2bfloat16(f);
  unsigned short u; __builtin_memcpy(&u, &h, 2); return u;
}
__device__ __forceinline__ float b2f(unsigned short u) {
  return __uint_as_float(((unsigned)u) << 16);
}

// ---------------- prep: x->bf16 (pad rows zeroed), W1->bf16 transposed,
//                  W2->bf16 transposed+padded to 64 cols, deg->0 ----------------

__global__ __launch_bounds__(256) void prep_k(const float* __restrict__ x,
                                              const float* __restrict__ W1,
                                              const float* __restrict__ W2,
                                              unsigned short* __restrict__ xb,
                                              unsigned short* __restrict__ w1t,
                                              unsigned short* __restrict__ w2t,
                                              int* __restrict__ deg) {
  int tid = blockIdx.x * 256 + threadIdx.x;
  if (tid < N_NODES) deg[tid] = 0;
  const int nx4 = MPAD * NFEAT / 4;          // 1,294,336
  const int nw1 = NFEAT * NHID;              // 131,072
  if (tid < nx4) {
    int i = tid * 4;
    int row = i / NFEAT;
    float4 v = make_float4(0.f, 0.f, 0.f, 0.f);
    if (row < N_NODES) v = *(const float4*)&x[i];
    ushort4 o;
    o.x = f2b(v.x); o.y = f2b(v.y); o.z = f2b(v.z); o.w = f2b(v.w);
    *(ushort4*)&xb[i] = o;
  } else if (tid < nx4 + nw1) {
    int j = tid - nx4;
    int k = j / NHID, n = j % NHID;            // coalesced read of W1
    w1t[n * NFEAT + k] = f2b(W1[j]);           // transposed bf16 write
  } else {
    int j = tid - nx4 - nw1;
    if (j < 64 * NHID) {
      int n = j >> 8;                          // out-col 0..63
      int k = j & 255;                         // k 0..255
      w2t[j] = (n < NCLASS) ? f2b(W2[k * NCLASS + n]) : (unsigned short)0;
    }
  }
}

// ---------------- CSR build ----------------

__global__ __launch_bounds__(256) void count_k(const int* __restrict__ dst,
                                               int* __restrict__ deg) {
  int e = blockIdx.x * 256 + threadIdx.x;
  if (e < N_EDGES) atomicAdd(&deg[dst[e]], 1);
}

// 1024 threads, two-level shfl scan — no serial section.
__global__ __launch_bounds__(1024) void scan_k(const int* __restrict__ deg,
                                               int* __restrict__ rp,
                                               int* __restrict__ nxt) {
  __shared__ int wsum[16];
  int t    = threadIdx.x;
  int lane = t & 63, wv = t >> 6;
  const int CH = 10;
  int lo = t * CH, hi = lo + CH;
  if (lo > N_NODES) lo = N_NODES;
  if (hi > N_NODES) hi = N_NODES;
  int s = 0;
#pragma unroll
  for (int jj = 0; jj < CH; jj++) {
    int j = lo + jj;
    if (j < hi) s += deg[j];
  }
  int inc = s;
#pragma unroll
  for (int off = 1; off < 64; off <<= 1) {
    int v = __shfl_up(inc, off);
    if (lane >= off) inc += v;
  }
  if (lane == 63) wsum[wv] = inc;
  __syncthreads();
  if (wv == 0) {
    int v = (lane < 16) ? wsum[lane] : 0;
    int vinc = v;
#pragma unroll
    for (int off = 1; off < 16; off <<= 1) {
      int u = __shfl_up(vinc, off);
      if (lane >= off) vinc += u;
    }
    if (lane < 16) wsum[lane] = vinc - v;
  }
  __syncthreads();
  int r = wsum[wv] + inc - s;
#pragma unroll
  for (int jj = 0; jj < CH; jj++) {
    int j = lo + jj;
    if (j < hi) { rp[j] = r; nxt[j] = r; r += deg[j]; }
  }
  if (hi == N_NODES) rp[N_NODES] = r;
}

// ---------------- fused: scatter (blocks < EB)  ||  GEMM1 128x64 MFMA ----------------
// scatter needs scan done; gemm1 needs only prep — independent, overlap in one launch.

__global__ __launch_bounds__(256) void scatter_gemm1_k(
    const int* __restrict__ src, const int* __restrict__ dst,
    const float* __restrict__ w, int* __restrict__ nxt, int2* __restrict__ epk,
    const unsigned short* __restrict__ xb, const unsigned short* __restrict__ w1t,
    unsigned short* __restrict__ xw1b) {
  if (blockIdx.x < EB) {
    int e = blockIdx.x * 256 + threadIdx.x;
    if (e < N_EDGES) {
      int d = dst[e];
      int p = atomicAdd(&nxt[d], 1);
      int2 pk; pk.x = src[e]; pk.y = __float_as_int(w[e]);
      epk[p] = pk;
    }
    return;
  }
  // ---- GEMM1 role: 128x64 tile, BK=32, 4 waves (2x2), 4x2 frags/wave ----
  __shared__ short8 As[128 * 4];   // 8 KB
  __shared__ short8 Bs[64 * 4];    // 4 KB

  const int b  = blockIdx.x - EB;
  const int bx = b % G1X;
  const int by = b / G1X;
  const int bm = bx * 128;
  const int bn = by * 64;
  const int t  = threadIdx.x;
  const int l  = t & 63;
  const int wv = t >> 6;
  const int wr = wv >> 1, wc = wv & 1;

  const int rowA = t >> 1, sA = (t & 1) * 2;   // 2 short8 per thread
  const int rowB = t >> 2, sB = t & 3;         // 1 short8 per thread

  const floatx4 zero = {0.f, 0.f, 0.f, 0.f};
  floatx4 acc[4][2];
#pragma unroll
  for (int mi = 0; mi < 4; mi++) { acc[mi][0] = zero; acc[mi][1] = zero; }

  const int q = l >> 4;

  for (int k0 = 0; k0 < NFEAT; k0 += 32) {
    short8 a0 = *(const short8*)&xb [(size_t)(bm + rowA) * NFEAT + k0 + sA * 8];
    short8 a1 = *(const short8*)&xb [(size_t)(bm + rowA) * NFEAT + k0 + sA * 8 + 8];
    short8 bv = *(const short8*)&w1t[(size_t)(bn + rowB) * NFEAT + k0 + sB * 8];
    __syncthreads();
    As[rowA * 4 + ((sA    ) ^ (rowA & 3))] = a0;
    As[rowA * 4 + ((sA + 1) ^ (rowA & 3))] = a1;
    Bs[rowB * 4 + (sB ^ (rowB & 3))] = bv;
    __syncthreads();

    short8 af[4], bf2[2];
#pragma unroll
    for (int mi = 0; mi < 4; mi++) {
      int ar = wr * 64 + mi * 16 + (l & 15);
      af[mi] = As[ar * 4 + (q ^ (ar & 3))];
    }
#pragma unroll
    for (int ni = 0; ni < 2; ni++) {
      int bc = wc * 32 + ni * 16 + (l & 15);
      bf2[ni] = Bs[bc * 4 + (q ^ (bc & 3))];
    }
#pragma unroll
    for (int mi = 0; mi < 4; mi++)
#pragma unroll
      for (int ni = 0; ni < 2; ni++)
        acc[mi][ni] = __builtin_amdgcn_mfma_f32_16x16x32_bf16(af[mi], bf2[ni], acc[mi][ni], 0, 0, 0);
  }

#pragma unroll
  for (int mi = 0; mi < 4; mi++)
#pragma unroll
    for (int ni = 0; ni < 2; ni++) {
      int row = bm + wr * 64 + mi * 16 + (l >> 4) * 4;
      int col = bn + wc * 32 + ni * 16 + (l & 15);
#pragma unroll
      for (int r = 0; r < 4; r++)
        xw1b[(size_t)(row + r) * NHID + col] = f2b(acc[mi][ni][r]);
    }
}

// ---------------- SpMM1: h = bf16(relu(A_csr * xw1 + b1)) ----------------
// block = 4 waves = 4 nodes of one 64-feat slice; slice tied to XCD via bid&7.
// 8 independent gathers in flight.

__global__ __launch_bounds__(256) void spmm1_k(const int* __restrict__ rp,
                                               const int2* __restrict__ epk,
                                               const unsigned short* __restrict__ xw1b,
                                               const float* __restrict__ b1,
                                               unsigned short* __restrict__ h) {
  int bid   = blockIdx.x;
  int xcd   = bid & 7;
  int slice = xcd >> 1;
  int half  = xcd & 1;
  int wave  = threadIdx.x >> 6;
  int lane  = threadIdx.x & 63;
  int node  = (bid >> 3) * 4 + wave + half * 5000;
  int f0    = slice * 64 + lane;

  int e0 = rp[node], e1 = rp[node + 1];
  float acc = 0.f;
  for (int base = e0; base < e1; base += 64) {
    int cnt = e1 - base; if (cnt > 64) cnt = 64;
    int2 my = make_int2(0, 0);
    if (lane < cnt) my = epk[base + lane];
    int j = 0;
    for (; j + 8 <= cnt; j += 8) {
      int   s0 = __shfl(my.x, j + 0); float w0 = __int_as_float(__shfl(my.y, j + 0));
      int   s1 = __shfl(my.x, j + 1); float w1 = __int_as_float(__shfl(my.y, j + 1));
      int   s2 = __shfl(my.x, j + 2); float w2 = __int_as_float(__shfl(my.y, j + 2));
      int   s3 = __shfl(my.x, j + 3); float w3 = __int_as_float(__shfl(my.y, j + 3));
      int   s4 = __shfl(my.x, j + 4); float w4 = __int_as_float(__shfl(my.y, j + 4));
      int   s5 = __shfl(my.x, j + 5); float w5 = __int_as_float(__shfl(my.y, j + 5));
      int   s6 = __shfl(my.x, j + 6); float w6 = __int_as_float(__shfl(my.y, j + 6));
      int   s7 = __shfl(my.x, j + 7); float w7 = __int_as_float(__shfl(my.y, j + 7));
      float v0 = b2f(xw1b[(size_t)s0 * NHID + f0]);
      float v1 = b2f(xw1b[(size_t)s1 * NHID + f0]);
      float v2 = b2f(xw1b[(size_t)s2 * NHID + f0]);
      float v3 = b2f(xw1b[(size_t)s3 * NHID + f0]);
      float v4 = b2f(xw1b[(size_t)s4 * NHID + f0]);
      float v5 = b2f(xw1b[(size_t)s5 * NHID + f0]);
      float v6 = b2f(xw1b[(size_t)s6 * NHID + f0]);
      float v7 = b2f(xw1b[(size_t)s7 * NHID + f0]);
      acc = fmaf(w0, v0, acc); acc = fmaf(w1, v1, acc);
      acc = fmaf(w2, v2, acc); acc = fmaf(w3, v3, acc);
      acc = fmaf(w4, v4, acc); acc = fmaf(w5, v5, acc);
      acc = fmaf(w6, v6, acc); acc = fmaf(w7, v7, acc);
    }
    for (; j < cnt; j++) {
      int   sj = __shfl(my.x, j);
      float wj = __int_as_float(__shfl(my.y, j));
      acc = fmaf(wj, b2f(xw1b[(size_t)sj * NHID + f0]), acc);
    }
  }
  acc += b1[f0];
  h[(size_t)node * NHID + f0] = f2b(fmaxf(acc, 0.f));
}

// ---------------- GEMM2: hw2 = h @ W2  via MFMA, 64x64 tile, K=256 ----------------
// hw2 padded to 64 cols (cols >= NCLASS are garbage, never read).

__global__ __launch_bounds__(256) void gemm2_k(const unsigned short* __restrict__ h,
                                               const unsigned short* __restrict__ w2t,
                                               float* __restrict__ hw2) {
  __shared__ short8 As[64 * 4];
  __shared__ short8 Bs[64 * 4];

  const int t  = threadIdx.x;
  const int bm = blockIdx.x * 64;
  const int l  = t & 63;
  const int wv = t >> 6;
  const int wr = wv >> 1, wc = wv & 1;
  const int srow = t >> 2, sslot = t & 3;

  const floatx4 zero = {0.f, 0.f, 0.f, 0.f};
  floatx4 acc[2][2];
  acc[0][0] = zero; acc[0][1] = zero; acc[1][0] = zero; acc[1][1] = zero;

  const int q = l >> 4;

  for (int k0 = 0; k0 < NHID; k0 += 32) {
    short8 av = *(const short8*)&h  [(size_t)(bm + srow) * NHID + k0 + sslot * 8];
    short8 bv = *(const short8*)&w2t[(size_t)srow * NHID + k0 + sslot * 8];
    __syncthreads();
    As[srow * 4 + (sslot ^ (srow & 3))] = av;
    Bs[srow * 4 + (sslot ^ (srow & 3))] = bv;
    __syncthreads();

    short8 af[2], bf2[2];
#pragma unroll
    for (int mi = 0; mi < 2; mi++) {
      int ar = wr * 32 + mi * 16 + (l & 15);
      af[mi] = As[ar * 4 + (q ^ (ar & 3))];
    }
#pragma unroll
    for (int ni = 0; ni < 2; ni++) {
      int bc = wc * 32 + ni * 16 + (l & 15);
      bf2[ni] = Bs[bc * 4 + (q ^ (bc & 3))];
    }
#pragma unroll
    for (int mi = 0; mi < 2; mi++)
#pragma unroll
      for (int ni = 0; ni < 2; ni++)
        acc[mi][ni] = __builtin_amdgcn_mfma_f32_16x16x32_bf16(af[mi], bf2[ni], acc[mi][ni], 0, 0, 0);
  }

#pragma unroll
  for (int mi = 0; mi < 2; mi++)
#pragma unroll
    for (int ni = 0; ni < 2; ni++) {
      int row = bm + wr * 32 + mi * 16 + (l >> 4) * 4;
      int col = wc * 32 + ni * 16 + (l & 15);
#pragma unroll
      for (int r = 0; r < 4; r++)
        hw2[(size_t)(row + r) * 64 + col] = acc[mi][ni][r];
    }
}

// ---------------- SpMM2 + b2 + log_softmax -> out (4 waves = 4 nodes/block) ----------------

__global__ __launch_bounds__(256) void spmm2_k(const int* __restrict__ rp,
                                               const int2* __restrict__ epk,
                                               const float* __restrict__ hw2,
                                               const float* __restrict__ b2,
                                               float* __restrict__ out) {
  int wave = threadIdx.x >> 6;
  int lane = threadIdx.x & 63;
  int i    = blockIdx.x * 4 + wave;
  bool act = (lane < NCLASS);
  int e0 = rp[i], e1 = rp[i + 1];
  float acc = act ? b2[lane] : 0.f;
  for (int base = e0; base < e1; base += 64) {
    int cnt = e1 - base; if (cnt > 64) cnt = 64;
    int2 my = make_int2(0, 0);
    if (lane < cnt) my = epk[base + lane];
    int j = 0;
    for (; j + 4 <= cnt; j += 4) {
      int   s0 = __shfl(my.x, j + 0); float w0 = __int_as_float(__shfl(my.y, j + 0));
      int   s1 = __shfl(my.x, j + 1); float w1 = __int_as_float(__shfl(my.y, j + 1));
      int   s2 = __shfl(my.x, j + 2); float w2 = __int_as_float(__shfl(my.y, j + 2));
      int   s3 = __shfl(my.x, j + 3); float w3 = __int_as_float(__shfl(my.y, j + 3));
      if (act) {
        float v0 = hw2[(size_t)s0 * 64 + lane];
        float v1 = hw2[(size_t)s1 * 64 + lane];
        float v2 = hw2[(size_t)s2 * 64 + lane];
        float v3 = hw2[(size_t)s3 * 64 + lane];
        acc = fmaf(w0, v0, acc);
        acc = fmaf(w1, v1, acc);
        acc = fmaf(w2, v2, acc);
        acc = fmaf(w3, v3, acc);
      }
    }
    for (; j < cnt; j++) {
      int   sj = __shfl(my.x, j);
      float wj = __int_as_float(__shfl(my.y, j));
      if (act) acc = fmaf(wj, hw2[(size_t)sj * 64 + lane], acc);
    }
  }
  float v = act ? acc : -INFINITY;
#pragma unroll
  for (int o = 32; o > 0; o >>= 1) v = fmaxf(v, __shfl_xor(v, o));
  float m  = v;
  float ex = act ? expf(acc - m) : 0.f;
  float s  = ex;
#pragma unroll
  for (int o = 32; o > 0; o >>= 1) s += __shfl_xor(s, o);
  float ls = logf(s);
  if (act) out[(size_t)i * NCLASS + lane] = acc - m - ls;
}

// ---------------- launcher ----------------

static inline size_t align256(size_t v) { return (v + 255) & ~(size_t)255; }

extern "C" void kernel_launch(void* const* d_in, const int* in_sizes, int n_in,
                              void* d_out, int out_size, void* d_ws, size_t ws_size,
                              hipStream_t stream) {
  const float* x        = (const float*)d_in[0];
  const int*   edge_src = (const int*)  d_in[1];
  const int*   edge_dst = (const int*)  d_in[2];
  const float* edge_w   = (const float*)d_in[3];
  const float* W1       = (const float*)d_in[4];
  const float* b1       = (const float*)d_in[5];
  const float* W2       = (const float*)d_in[6];
  const float* b2       = (const float*)d_in[7];
  float* out = (float*)d_out;

  char* ws = (char*)d_ws;
  size_t off = 0;
  unsigned short* xb   = (unsigned short*)(ws + off); off = align256(off + (size_t)MPAD * NFEAT * 2);
  unsigned short* w1t  = (unsigned short*)(ws + off); off = align256(off + (size_t)NFEAT * NHID * 2);
  unsigned short* w2t  = (unsigned short*)(ws + off); off = align256(off + (size_t)64 * NHID * 2);
  unsigned short* xw1b = (unsigned short*)(ws + off); off = align256(off + (size_t)MPAD * NHID * 2);
  unsigned short* h    = (unsigned short*)(ws + off); off = align256(off + (size_t)MPAD * NHID * 2);
  float* hw2 = (float*)(ws + off); off = align256(off + (size_t)MPAD * 64 * 4);
  int*   deg = (int*)  (ws + off); off = align256(off + (size_t)N_NODES * 4);
  int*   rp  = (int*)  (ws + off); off = align256(off + (size_t)(N_NODES + 4) * 4);
  int*   nxt = (int*)  (ws + off); off = align256(off + (size_t)N_NODES * 4);
  int2*  epk = (int2*) (ws + off); off = align256(off + (size_t)N_EDGES * 8);

  const int PREP_ITEMS = MPAD * NFEAT / 4 + NFEAT * NHID + 64 * NHID;
  prep_k<<<(PREP_ITEMS + 255) / 256, 256, 0, stream>>>(x, W1, W2, xb, w1t, w2t, deg);

  count_k<<<EB, 256, 0, stream>>>(edge_dst, deg);
  scan_k <<<1, 1024, 0, stream>>>(deg, rp, nxt);

  scatter_gemm1_k<<<EB + G1X * G1Y, 256, 0, stream>>>(edge_src, edge_dst, edge_w,
                                                      nxt, epk, xb, w1t, xw1b);

  spmm1_k<<<10000, 256, 0, stream>>>(rp, epk, xw1b, b1, h);

  gemm2_k<<<MPAD / 64, 256, 0, stream>>>(h, w2t, hw2);

  spmm2_k<<<2500, 256, 0, stream>>>(rp, epk, hw2, b2, out);
}

// Round 7
// 113.922 us; speedup vs baseline: 2.1002x; 1.1176x over previous
//
#include <hip/hip_runtime.h>
#include <hip/hip_bf16.h>
#include <math.h>

#define N_NODES 10000
#define MPAD    10112      // 79 * 128
#define N_EDGES 320000
#define NFEAT   512
#define NHID    256
#define NCLASS  40
#define EB      ((N_EDGES + 255) / 256)   // 1250
#define G1X     (MPAD / 128)              // 79
#define G1Y     (NHID / 64)               // 4

typedef short  short8  __attribute__((ext_vector_type(8)));
typedef float  floatx4 __attribute__((ext_vector_type(4)));

__device__ __forceinline__ unsigned short f2b(float f) {
  __hip_bfloat16 h = __float2bfloat16(f);
  unsigned short u; __builtin_memcpy(&u, &h, 2); return u;
}
__device__ __forceinline__ float b2f(unsigned short u) {
  return __uint_as_float(((unsigned)u) << 16);
}

// ---------------- prep: x->bf16 (pad rows zeroed), W1->bf16 transposed,
//                  W2->bf16 transposed+padded to 64 cols, deg->0 ----------------

__global__ __launch_bounds__(256) void prep_k(const float* __restrict__ x,
                                              const float* __restrict__ W1,
                                              const float* __restrict__ W2,
                                              unsigned short* __restrict__ xb,
                                              unsigned short* __restrict__ w1t,
                                              unsigned short* __restrict__ w2t,
                                              int* __restrict__ deg) {
  int tid = blockIdx.x * 256 + threadIdx.x;
  if (tid < N_NODES) deg[tid] = 0;
  const int nx4 = MPAD * NFEAT / 4;          // 1,294,336
  const int nw1 = NFEAT * NHID;              // 131,072
  if (tid < nx4) {
    int i = tid * 4;
    int row = i / NFEAT;
    float4 v = make_float4(0.f, 0.f, 0.f, 0.f);
    if (row < N_NODES) v = *(const float4*)&x[i];
    ushort4 o;
    o.x = f2b(v.x); o.y = f2b(v.y); o.z = f2b(v.z); o.w = f2b(v.w);
    *(ushort4*)&xb[i] = o;
  } else if (tid < nx4 + nw1) {
    int j = tid - nx4;
    int k = j / NHID, n = j % NHID;            // coalesced read of W1
    w1t[n * NFEAT + k] = f2b(W1[j]);           // transposed bf16 write
  } else {
    int j = tid - nx4 - nw1;
    if (j < 64 * NHID) {
      int n = j >> 8;                          // out-col 0..63
      int k = j & 255;                         // k 0..255
      w2t[j] = (n < NCLASS) ? f2b(W2[k * NCLASS + n]) : (unsigned short)0;
    }
  }
}

// ---------------- CSR build ----------------

__global__ __launch_bounds__(256) void count_k(const int* __restrict__ dst,
                                               int* __restrict__ deg) {
  int e = blockIdx.x * 256 + threadIdx.x;
  if (e < N_EDGES) atomicAdd(&deg[dst[e]], 1);
}

// 1024 threads, two-level shfl scan — no serial section.
__global__ __launch_bounds__(1024) void scan_k(const int* __restrict__ deg,
                                               int* __restrict__ rp,
                                               int* __restrict__ nxt) {
  __shared__ int wsum[16];
  int t    = threadIdx.x;
  int lane = t & 63, wv = t >> 6;
  const int CH = 10;
  int lo = t * CH, hi = lo + CH;
  if (lo > N_NODES) lo = N_NODES;
  if (hi > N_NODES) hi = N_NODES;
  int s = 0;
#pragma unroll
  for (int jj = 0; jj < CH; jj++) {
    int j = lo + jj;
    if (j < hi) s += deg[j];
  }
  int inc = s;
#pragma unroll
  for (int off = 1; off < 64; off <<= 1) {
    int v = __shfl_up(inc, off);
    if (lane >= off) inc += v;
  }
  if (lane == 63) wsum[wv] = inc;
  __syncthreads();
  if (wv == 0) {
    int v = (lane < 16) ? wsum[lane] : 0;
    int vinc = v;
#pragma unroll
    for (int off = 1; off < 16; off <<= 1) {
      int u = __shfl_up(vinc, off);
      if (lane >= off) vinc += u;
    }
    if (lane < 16) wsum[lane] = vinc - v;
  }
  __syncthreads();
  int r = wsum[wv] + inc - s;
#pragma unroll
  for (int jj = 0; jj < CH; jj++) {
    int j = lo + jj;
    if (j < hi) { rp[j] = r; nxt[j] = r; r += deg[j]; }
  }
  if (hi == N_NODES) rp[N_NODES] = r;
}

// ---------------- fused: scatter (blocks < EB)  ||  GEMM1 128x64 MFMA ----------------

__global__ __launch_bounds__(256) void scatter_gemm1_k(
    const int* __restrict__ src, const int* __restrict__ dst,
    const float* __restrict__ w, int* __restrict__ nxt, int2* __restrict__ epk,
    const unsigned short* __restrict__ xb, const unsigned short* __restrict__ w1t,
    unsigned short* __restrict__ xw1b) {
  if (blockIdx.x < EB) {
    int e = blockIdx.x * 256 + threadIdx.x;
    if (e < N_EDGES) {
      int d = dst[e];
      int p = atomicAdd(&nxt[d], 1);
      int2 pk; pk.x = src[e]; pk.y = __float_as_int(w[e]);
      epk[p] = pk;
    }
    return;
  }
  __shared__ short8 As[128 * 4];   // 8 KB
  __shared__ short8 Bs[64 * 4];    // 4 KB

  const int b  = blockIdx.x - EB;
  const int bx = b % G1X;
  const int by = b / G1X;
  const int bm = bx * 128;
  const int bn = by * 64;
  const int t  = threadIdx.x;
  const int l  = t & 63;
  const int wv = t >> 6;
  const int wr = wv >> 1, wc = wv & 1;

  const int rowA = t >> 1, sA = (t & 1) * 2;
  const int rowB = t >> 2, sB = t & 3;

  const floatx4 zero = {0.f, 0.f, 0.f, 0.f};
  floatx4 acc[4][2];
#pragma unroll
  for (int mi = 0; mi < 4; mi++) { acc[mi][0] = zero; acc[mi][1] = zero; }

  const int q = l >> 4;

  for (int k0 = 0; k0 < NFEAT; k0 += 32) {
    short8 a0 = *(const short8*)&xb [(size_t)(bm + rowA) * NFEAT + k0 + sA * 8];
    short8 a1 = *(const short8*)&xb [(size_t)(bm + rowA) * NFEAT + k0 + sA * 8 + 8];
    short8 bv = *(const short8*)&w1t[(size_t)(bn + rowB) * NFEAT + k0 + sB * 8];
    __syncthreads();
    As[rowA * 4 + ((sA    ) ^ (rowA & 3))] = a0;
    As[rowA * 4 + ((sA + 1) ^ (rowA & 3))] = a1;
    Bs[rowB * 4 + (sB ^ (rowB & 3))] = bv;
    __syncthreads();

    short8 af[4], bf2[2];
#pragma unroll
    for (int mi = 0; mi < 4; mi++) {
      int ar = wr * 64 + mi * 16 + (l & 15);
      af[mi] = As[ar * 4 + (q ^ (ar & 3))];
    }
#pragma unroll
    for (int ni = 0; ni < 2; ni++) {
      int bc = wc * 32 + ni * 16 + (l & 15);
      bf2[ni] = Bs[bc * 4 + (q ^ (bc & 3))];
    }
#pragma unroll
    for (int mi = 0; mi < 4; mi++)
#pragma unroll
      for (int ni = 0; ni < 2; ni++)
        acc[mi][ni] = __builtin_amdgcn_mfma_f32_16x16x32_bf16(af[mi], bf2[ni], acc[mi][ni], 0, 0, 0);
  }

#pragma unroll
  for (int mi = 0; mi < 4; mi++)
#pragma unroll
    for (int ni = 0; ni < 2; ni++) {
      int row = bm + wr * 64 + mi * 16 + (l >> 4) * 4;
      int col = bn + wc * 32 + ni * 16 + (l & 15);
#pragma unroll
      for (int r = 0; r < 4; r++)
        xw1b[(size_t)(row + r) * NHID + col] = f2b(acc[mi][ni][r]);
    }
}

// ---------------- SpMM1: h = bf16(relu(A_csr * xw1 + b1)) ----------------
// 2 slices of 128 feats; lane gathers uint (2 bf16). 8 XCD roles:
// xcd>>2 = slice (2.57 MB, L2-resident), xcd&3 = node quarter.
// 5000 blocks x 4 waves = 4 nodes/block. 8 gathers in flight.

__global__ __launch_bounds__(256) void spmm1_k(const int* __restrict__ rp,
                                               const int2* __restrict__ epk,
                                               const unsigned short* __restrict__ xw1b,
                                               const float* __restrict__ b1,
                                               unsigned short* __restrict__ h) {
  int bid     = blockIdx.x;
  int xcd     = bid & 7;
  int slice   = xcd >> 2;                 // 0..1
  int quarter = xcd & 3;                  // 0..3
  int wave    = threadIdx.x >> 6;
  int lane    = threadIdx.x & 63;
  int node    = (bid >> 3) * 4 + wave + quarter * 2500;
  int f0      = slice * 128 + lane * 2;   // element index

  int e0 = rp[node], e1 = rp[node + 1];
  float accx = 0.f, accy = 0.f;
  for (int base = e0; base < e1; base += 64) {
    int cnt = e1 - base; if (cnt > 64) cnt = 64;
    int2 my = make_int2(0, 0);
    if (lane < cnt) my = epk[base + lane];
    int j = 0;
    for (; j + 8 <= cnt; j += 8) {
      int   s0 = __shfl(my.x, j + 0); float w0 = __int_as_float(__shfl(my.y, j + 0));
      int   s1 = __shfl(my.x, j + 1); float w1 = __int_as_float(__shfl(my.y, j + 1));
      int   s2 = __shfl(my.x, j + 2); float w2 = __int_as_float(__shfl(my.y, j + 2));
      int   s3 = __shfl(my.x, j + 3); float w3 = __int_as_float(__shfl(my.y, j + 3));
      int   s4 = __shfl(my.x, j + 4); float w4 = __int_as_float(__shfl(my.y, j + 4));
      int   s5 = __shfl(my.x, j + 5); float w5 = __int_as_float(__shfl(my.y, j + 5));
      int   s6 = __shfl(my.x, j + 6); float w6 = __int_as_float(__shfl(my.y, j + 6));
      int   s7 = __shfl(my.x, j + 7); float w7 = __int_as_float(__shfl(my.y, j + 7));
      unsigned v0 = *(const unsigned*)&xw1b[(size_t)s0 * NHID + f0];
      unsigned v1 = *(const unsigned*)&xw1b[(size_t)s1 * NHID + f0];
      unsigned v2 = *(const unsigned*)&xw1b[(size_t)s2 * NHID + f0];
      unsigned v3 = *(const unsigned*)&xw1b[(size_t)s3 * NHID + f0];
      unsigned v4 = *(const unsigned*)&xw1b[(size_t)s4 * NHID + f0];
      unsigned v5 = *(const unsigned*)&xw1b[(size_t)s5 * NHID + f0];
      unsigned v6 = *(const unsigned*)&xw1b[(size_t)s6 * NHID + f0];
      unsigned v7 = *(const unsigned*)&xw1b[(size_t)s7 * NHID + f0];
      accx = fmaf(w0, b2f((unsigned short)(v0 & 0xffff)), accx);
      accy = fmaf(w0, b2f((unsigned short)(v0 >> 16)),    accy);
      accx = fmaf(w1, b2f((unsigned short)(v1 & 0xffff)), accx);
      accy = fmaf(w1, b2f((unsigned short)(v1 >> 16)),    accy);
      accx = fmaf(w2, b2f((unsigned short)(v2 & 0xffff)), accx);
      accy = fmaf(w2, b2f((unsigned short)(v2 >> 16)),    accy);
      accx = fmaf(w3, b2f((unsigned short)(v3 & 0xffff)), accx);
      accy = fmaf(w3, b2f((unsigned short)(v3 >> 16)),    accy);
      accx = fmaf(w4, b2f((unsigned short)(v4 & 0xffff)), accx);
      accy = fmaf(w4, b2f((unsigned short)(v4 >> 16)),    accy);
      accx = fmaf(w5, b2f((unsigned short)(v5 & 0xffff)), accx);
      accy = fmaf(w5, b2f((unsigned short)(v5 >> 16)),    accy);
      accx = fmaf(w6, b2f((unsigned short)(v6 & 0xffff)), accx);
      accy = fmaf(w6, b2f((unsigned short)(v6 >> 16)),    accy);
      accx = fmaf(w7, b2f((unsigned short)(v7 & 0xffff)), accx);
      accy = fmaf(w7, b2f((unsigned short)(v7 >> 16)),    accy);
    }
    for (; j < cnt; j++) {
      int   sj = __shfl(my.x, j);
      float wj = __int_as_float(__shfl(my.y, j));
      unsigned v = *(const unsigned*)&xw1b[(size_t)sj * NHID + f0];
      accx = fmaf(wj, b2f((unsigned short)(v & 0xffff)), accx);
      accy = fmaf(wj, b2f((unsigned short)(v >> 16)),    accy);
    }
  }
  accx += b1[f0];
  accy += b1[f0 + 1];
  unsigned po = ((unsigned)f2b(fmaxf(accy, 0.f)) << 16) | f2b(fmaxf(accx, 0.f));
  *(unsigned*)&h[(size_t)node * NHID + f0] = po;
}

// ---------------- GEMM2: hw2 = h @ W2  via MFMA, 64x64 tile, K=256 ----------------

__global__ __launch_bounds__(256) void gemm2_k(const unsigned short* __restrict__ h,
                                               const unsigned short* __restrict__ w2t,
                                               float* __restrict__ hw2) {
  __shared__ short8 As[64 * 4];
  __shared__ short8 Bs[64 * 4];

  const int t  = threadIdx.x;
  const int bm = blockIdx.x * 64;
  const int l  = t & 63;
  const int wv = t >> 6;
  const int wr = wv >> 1, wc = wv & 1;
  const int srow = t >> 2, sslot = t & 3;

  const floatx4 zero = {0.f, 0.f, 0.f, 0.f};
  floatx4 acc[2][2];
  acc[0][0] = zero; acc[0][1] = zero; acc[1][0] = zero; acc[1][1] = zero;

  const int q = l >> 4;

  for (int k0 = 0; k0 < NHID; k0 += 32) {
    short8 av = *(const short8*)&h  [(size_t)(bm + srow) * NHID + k0 + sslot * 8];
    short8 bv = *(const short8*)&w2t[(size_t)srow * NHID + k0 + sslot * 8];
    __syncthreads();
    As[srow * 4 + (sslot ^ (srow & 3))] = av;
    Bs[srow * 4 + (sslot ^ (srow & 3))] = bv;
    __syncthreads();

    short8 af[2], bf2[2];
#pragma unroll
    for (int mi = 0; mi < 2; mi++) {
      int ar = wr * 32 + mi * 16 + (l & 15);
      af[mi] = As[ar * 4 + (q ^ (ar & 3))];
    }
#pragma unroll
    for (int ni = 0; ni < 2; ni++) {
      int bc = wc * 32 + ni * 16 + (l & 15);
      bf2[ni] = Bs[bc * 4 + (q ^ (bc & 3))];
    }
#pragma unroll
    for (int mi = 0; mi < 2; mi++)
#pragma unroll
      for (int ni = 0; ni < 2; ni++)
        acc[mi][ni] = __builtin_amdgcn_mfma_f32_16x16x32_bf16(af[mi], bf2[ni], acc[mi][ni], 0, 0, 0);
  }

#pragma unroll
  for (int mi = 0; mi < 2; mi++)
#pragma unroll
    for (int ni = 0; ni < 2; ni++) {
      int row = bm + wr * 32 + mi * 16 + (l >> 4) * 4;
      int col = wc * 32 + ni * 16 + (l & 15);
#pragma unroll
      for (int r = 0; r < 4; r++)
        hw2[(size_t)(row + r) * 64 + col] = acc[mi][ni][r];
    }
}

// ---------------- SpMM2 + b2 + log_softmax -> out (4 waves = 4 nodes/block) ----------------

__global__ __launch_bounds__(256) void spmm2_k(const int* __restrict__ rp,
                                               const int2* __restrict__ epk,
                                               const float* __restrict__ hw2,
                                               const float* __restrict__ b2,
                                               float* __restrict__ out) {
  int wave = threadIdx.x >> 6;
  int lane = threadIdx.x & 63;
  int i    = blockIdx.x * 4 + wave;
  bool act = (lane < NCLASS);
  int e0 = rp[i], e1 = rp[i + 1];
  float acc = act ? b2[lane] : 0.f;
  for (int base = e0; base < e1; base += 64) {
    int cnt = e1 - base; if (cnt > 64) cnt = 64;
    int2 my = make_int2(0, 0);
    if (lane < cnt) my = epk[base + lane];
    int j = 0;
    for (; j + 8 <= cnt; j += 8) {
      int   s0 = __shfl(my.x, j + 0); float w0 = __int_as_float(__shfl(my.y, j + 0));
      int   s1 = __shfl(my.x, j + 1); float w1 = __int_as_float(__shfl(my.y, j + 1));
      int   s2 = __shfl(my.x, j + 2); float w2 = __int_as_float(__shfl(my.y, j + 2));
      int   s3 = __shfl(my.x, j + 3); float w3 = __int_as_float(__shfl(my.y, j + 3));
      int   s4 = __shfl(my.x, j + 4); float w4 = __int_as_float(__shfl(my.y, j + 4));
      int   s5 = __shfl(my.x, j + 5); float w5 = __int_as_float(__shfl(my.y, j + 5));
      int   s6 = __shfl(my.x, j + 6); float w6 = __int_as_float(__shfl(my.y, j + 6));
      int   s7 = __shfl(my.x, j + 7); float w7 = __int_as_float(__shfl(my.y, j + 7));
      if (act) {
        float v0 = hw2[(size_t)s0 * 64 + lane];
        float v1 = hw2[(size_t)s1 * 64 + lane];
        float v2 = hw2[(size_t)s2 * 64 + lane];
        float v3 = hw2[(size_t)s3 * 64 + lane];
        float v4 = hw2[(size_t)s4 * 64 + lane];
        float v5 = hw2[(size_t)s5 * 64 + lane];
        float v6 = hw2[(size_t)s6 * 64 + lane];
        float v7 = hw2[(size_t)s7 * 64 + lane];
        acc = fmaf(w0, v0, acc); acc = fmaf(w1, v1, acc);
        acc = fmaf(w2, v2, acc); acc = fmaf(w3, v3, acc);
        acc = fmaf(w4, v4, acc); acc = fmaf(w5, v5, acc);
        acc = fmaf(w6, v6, acc); acc = fmaf(w7, v7, acc);
      }
    }
    for (; j < cnt; j++) {
      int   sj = __shfl(my.x, j);
      float wj = __int_as_float(__shfl(my.y, j));
      if (act) acc = fmaf(wj, hw2[(size_t)sj * 64 + lane], acc);
    }
  }
  float v = act ? acc : -INFINITY;
#pragma unroll
  for (int o = 32; o > 0; o >>= 1) v = fmaxf(v, __shfl_xor(v, o));
  float m  = v;
  float ex = act ? expf(acc - m) : 0.f;
  float s  = ex;
#pragma unroll
  for (int o = 32; o > 0; o >>= 1) s += __shfl_xor(s, o);
  float ls = logf(s);
  if (act) out[(size_t)i * NCLASS + lane] = acc - m - ls;
}

// ---------------- launcher ----------------

static inline size_t align256(size_t v) { return (v + 255) & ~(size_t)255; }

extern "C" void kernel_launch(void* const* d_in, const int* in_sizes, int n_in,
                              void* d_out, int out_size, void* d_ws, size_t ws_size,
                              hipStream_t stream) {
  const float* x        = (const float*)d_in[0];
  const int*   edge_src = (const int*)  d_in[1];
  const int*   edge_dst = (const int*)  d_in[2];
  const float* edge_w   = (const float*)d_in[3];
  const float* W1       = (const float*)d_in[4];
  const float* b1       = (const float*)d_in[5];
  const float* W2       = (const float*)d_in[6];
  const float* b2       = (const float*)d_in[7];
  float* out = (float*)d_out;

  char* ws = (char*)d_ws;
  size_t off = 0;
  unsigned short* xb   = (unsigned short*)(ws + off); off = align256(off + (size_t)MPAD * NFEAT * 2);
  unsigned short* w1t  = (unsigned short*)(ws + off); off = align256(off + (size_t)NFEAT * NHID * 2);
  unsigned short* w2t  = (unsigned short*)(ws + off); off = align256(off + (size_t)64 * NHID * 2);
  unsigned short* xw1b = (unsigned short*)(ws + off); off = align256(off + (size_t)MPAD * NHID * 2);
  unsigned short* h    = (unsigned short*)(ws + off); off = align256(off + (size_t)MPAD * NHID * 2);
  float* hw2 = (float*)(ws + off); off = align256(off + (size_t)MPAD * 64 * 4);
  int*   deg = (int*)  (ws + off); off = align256(off + (size_t)N_NODES * 4);
  int*   rp  = (int*)  (ws + off); off = align256(off + (size_t)(N_NODES + 4) * 4);
  int*   nxt = (int*)  (ws + off); off = align256(off + (size_t)N_NODES * 4);
  int2*  epk = (int2*) (ws + off); off = align256(off + (size_t)N_EDGES * 8);

  const int PREP_ITEMS = MPAD * NFEAT / 4 + NFEAT * NHID + 64 * NHID;
  prep_k<<<(PREP_ITEMS + 255) / 256, 256, 0, stream>>>(x, W1, W2, xb, w1t, w2t, deg);

  count_k<<<EB, 256, 0, stream>>>(edge_dst, deg);
  scan_k <<<1, 1024, 0, stream>>>(deg, rp, nxt);

  scatter_gemm1_k<<<EB + G1X * G1Y, 256, 0, stream>>>(edge_src, edge_dst, edge_w,
                                                      nxt, epk, xb, w1t, xw1b);

  spmm1_k<<<5000, 256, 0, stream>>>(rp, epk, xw1b, b1, h);

  gemm2_k<<<MPAD / 64, 256, 0, stream>>>(h, w2t, hw2);

  spmm2_k<<<2500, 256, 0, stream>>>(rp, epk, hw2, b2, out);
}

// Round 8
// 82.059 us; speedup vs baseline: 2.9156x; 1.3883x over previous
//
#include <hip/hip_runtime.h>
#include <hip/hip_bf16.h>
#include <math.h>

#define N_NODES 10000
#define MPAD    10112      // 79 * 128
#define N_EDGES 320000
#define NFEAT   512
#define NHID    256
#define NCLASS  40
#define SLOT    96         // max deg bound: Binom(320K,1e-4) max ~55; P(>96) ~ 0
#define EB      ((N_EDGES + 255) / 256)   // 1250
#define G1X     (MPAD / 128)              // 79
#define G1Y     (NHID / 64)               // 4

typedef short  short8  __attribute__((ext_vector_type(8)));
typedef float  floatx4 __attribute__((ext_vector_type(4)));

__device__ __forceinline__ unsigned short f2b(float f) {
  __hip_bfloat16 h = __float2bfloat16(f);
  unsigned short u; __builtin_memcpy(&u, &h, 2); return u;
}
__device__ __forceinline__ float b2f(unsigned short u) {
  return __uint_as_float(((unsigned)u) << 16);
}

// ---------------- prep: x->bf16 (pad rows zeroed), W1->bf16 transposed,
//                  W2->bf16 transposed+padded to 64 cols, cnt->0 ----------------

__global__ __launch_bounds__(256) void prep_k(const float* __restrict__ x,
                                              const float* __restrict__ W1,
                                              const float* __restrict__ W2,
                                              unsigned short* __restrict__ xb,
                                              unsigned short* __restrict__ w1t,
                                              unsigned short* __restrict__ w2t,
                                              int* __restrict__ cnt) {
  int tid = blockIdx.x * 256 + threadIdx.x;
  if (tid < N_NODES) cnt[tid] = 0;
  const int nx4 = MPAD * NFEAT / 4;          // 1,294,336
  const int nw1 = NFEAT * NHID;              // 131,072
  if (tid < nx4) {
    int i = tid * 4;
    int row = i / NFEAT;
    float4 v = make_float4(0.f, 0.f, 0.f, 0.f);
    if (row < N_NODES) v = *(const float4*)&x[i];
    ushort4 o;
    o.x = f2b(v.x); o.y = f2b(v.y); o.z = f2b(v.z); o.w = f2b(v.w);
    *(ushort4*)&xb[i] = o;
  } else if (tid < nx4 + nw1) {
    int j = tid - nx4;
    int k = j / NHID, n = j % NHID;            // coalesced read of W1
    w1t[n * NFEAT + k] = f2b(W1[j]);           // transposed bf16 write
  } else {
    int j = tid - nx4 - nw1;
    if (j < 64 * NHID) {
      int n = j >> 8;                          // out-col 0..63
      int k = j & 255;                         // k 0..255
      w2t[j] = (n < NCLASS) ? f2b(W2[k * NCLASS + n]) : (unsigned short)0;
    }
  }
}

// ---------------- fused: slot-scatter (blocks < EB)  ||  GEMM1 128x64 MFMA ----------------
// Slot-CSR: node i's edges live at epk[i*SLOT .. i*SLOT+cnt[i]); no count/scan passes.

__global__ __launch_bounds__(256) void scatter_gemm1_k(
    const int* __restrict__ src, const int* __restrict__ dst,
    const float* __restrict__ w, int* __restrict__ cnt, int2* __restrict__ epk,
    const unsigned short* __restrict__ xb, const unsigned short* __restrict__ w1t,
    unsigned short* __restrict__ xw1b) {
  if (blockIdx.x < EB) {
    int e = blockIdx.x * 256 + threadIdx.x;
    if (e < N_EDGES) {
      int d = dst[e];
      int p = atomicAdd(&cnt[d], 1);
      int2 pk; pk.x = src[e]; pk.y = __float_as_int(w[e]);
      epk[d * SLOT + p] = pk;
    }
    return;
  }
  __shared__ short8 As[128 * 4];   // 8 KB
  __shared__ short8 Bs[64 * 4];    // 4 KB

  const int b  = blockIdx.x - EB;
  const int bx = b % G1X;
  const int by = b / G1X;
  const int bm = bx * 128;
  const int bn = by * 64;
  const int t  = threadIdx.x;
  const int l  = t & 63;
  const int wv = t >> 6;
  const int wr = wv >> 1, wc = wv & 1;

  const int rowA = t >> 1, sA = (t & 1) * 2;
  const int rowB = t >> 2, sB = t & 3;

  const floatx4 zero = {0.f, 0.f, 0.f, 0.f};
  floatx4 acc[4][2];
#pragma unroll
  for (int mi = 0; mi < 4; mi++) { acc[mi][0] = zero; acc[mi][1] = zero; }

  const int q = l >> 4;

  for (int k0 = 0; k0 < NFEAT; k0 += 32) {
    short8 a0 = *(const short8*)&xb [(size_t)(bm + rowA) * NFEAT + k0 + sA * 8];
    short8 a1 = *(const short8*)&xb [(size_t)(bm + rowA) * NFEAT + k0 + sA * 8 + 8];
    short8 bv = *(const short8*)&w1t[(size_t)(bn + rowB) * NFEAT + k0 + sB * 8];
    __syncthreads();
    As[rowA * 4 + ((sA    ) ^ (rowA & 3))] = a0;
    As[rowA * 4 + ((sA + 1) ^ (rowA & 3))] = a1;
    Bs[rowB * 4 + (sB ^ (rowB & 3))] = bv;
    __syncthreads();

    short8 af[4], bf2[2];
#pragma unroll
    for (int mi = 0; mi < 4; mi++) {
      int ar = wr * 64 + mi * 16 + (l & 15);
      af[mi] = As[ar * 4 + (q ^ (ar & 3))];
    }
#pragma unroll
    for (int ni = 0; ni < 2; ni++) {
      int bc = wc * 32 + ni * 16 + (l & 15);
      bf2[ni] = Bs[bc * 4 + (q ^ (bc & 3))];
    }
#pragma unroll
    for (int mi = 0; mi < 4; mi++)
#pragma unroll
      for (int ni = 0; ni < 2; ni++)
        acc[mi][ni] = __builtin_amdgcn_mfma_f32_16x16x32_bf16(af[mi], bf2[ni], acc[mi][ni], 0, 0, 0);
  }

#pragma unroll
  for (int mi = 0; mi < 4; mi++)
#pragma unroll
    for (int ni = 0; ni < 2; ni++) {
      int row = bm + wr * 64 + mi * 16 + (l >> 4) * 4;
      int col = bn + wc * 32 + ni * 16 + (l & 15);
#pragma unroll
      for (int r = 0; r < 4; r++)
        xw1b[(size_t)(row + r) * NHID + col] = f2b(acc[mi][ni][r]);
    }
}

// ---------------- SpMM1: h = bf16(relu(A * xw1 + b1)) ----------------
// 2 slices of 128 feats; lane gathers uint (2 bf16). xcd>>2 = slice
// (2.57 MB, L2-resident), xcd&3 = node quarter. 4 nodes/block.

__global__ __launch_bounds__(256) void spmm1_k(const int* __restrict__ cnt,
                                               const int2* __restrict__ epk,
                                               const unsigned short* __restrict__ xw1b,
                                               const float* __restrict__ b1,
                                               unsigned short* __restrict__ h) {
  int bid     = blockIdx.x;
  int xcd     = bid & 7;
  int slice   = xcd >> 2;                 // 0..1
  int quarter = xcd & 3;                  // 0..3
  int wave    = threadIdx.x >> 6;
  int lane    = threadIdx.x & 63;
  int node    = (bid >> 3) * 4 + wave + quarter * 2500;
  int f0      = slice * 128 + lane * 2;   // element index

  int e0 = node * SLOT;
  int n  = cnt[node];
  float accx = 0.f, accy = 0.f;
  for (int base = 0; base < n; base += 64) {
    int c2 = n - base; if (c2 > 64) c2 = 64;
    int2 my = make_int2(0, 0);
    if (lane < c2) my = epk[e0 + base + lane];
    int j = 0;
    for (; j + 8 <= c2; j += 8) {
      int   s0 = __shfl(my.x, j + 0); float w0 = __int_as_float(__shfl(my.y, j + 0));
      int   s1 = __shfl(my.x, j + 1); float w1 = __int_as_float(__shfl(my.y, j + 1));
      int   s2 = __shfl(my.x, j + 2); float w2 = __int_as_float(__shfl(my.y, j + 2));
      int   s3 = __shfl(my.x, j + 3); float w3 = __int_as_float(__shfl(my.y, j + 3));
      int   s4 = __shfl(my.x, j + 4); float w4 = __int_as_float(__shfl(my.y, j + 4));
      int   s5 = __shfl(my.x, j + 5); float w5 = __int_as_float(__shfl(my.y, j + 5));
      int   s6 = __shfl(my.x, j + 6); float w6 = __int_as_float(__shfl(my.y, j + 6));
      int   s7 = __shfl(my.x, j + 7); float w7 = __int_as_float(__shfl(my.y, j + 7));
      unsigned v0 = *(const unsigned*)&xw1b[(size_t)s0 * NHID + f0];
      unsigned v1 = *(const unsigned*)&xw1b[(size_t)s1 * NHID + f0];
      unsigned v2 = *(const unsigned*)&xw1b[(size_t)s2 * NHID + f0];
      unsigned v3 = *(const unsigned*)&xw1b[(size_t)s3 * NHID + f0];
      unsigned v4 = *(const unsigned*)&xw1b[(size_t)s4 * NHID + f0];
      unsigned v5 = *(const unsigned*)&xw1b[(size_t)s5 * NHID + f0];
      unsigned v6 = *(const unsigned*)&xw1b[(size_t)s6 * NHID + f0];
      unsigned v7 = *(const unsigned*)&xw1b[(size_t)s7 * NHID + f0];
      accx = fmaf(w0, b2f((unsigned short)(v0 & 0xffff)), accx);
      accy = fmaf(w0, b2f((unsigned short)(v0 >> 16)),    accy);
      accx = fmaf(w1, b2f((unsigned short)(v1 & 0xffff)), accx);
      accy = fmaf(w1, b2f((unsigned short)(v1 >> 16)),    accy);
      accx = fmaf(w2, b2f((unsigned short)(v2 & 0xffff)), accx);
      accy = fmaf(w2, b2f((unsigned short)(v2 >> 16)),    accy);
      accx = fmaf(w3, b2f((unsigned short)(v3 & 0xffff)), accx);
      accy = fmaf(w3, b2f((unsigned short)(v3 >> 16)),    accy);
      accx = fmaf(w4, b2f((unsigned short)(v4 & 0xffff)), accx);
      accy = fmaf(w4, b2f((unsigned short)(v4 >> 16)),    accy);
      accx = fmaf(w5, b2f((unsigned short)(v5 & 0xffff)), accx);
      accy = fmaf(w5, b2f((unsigned short)(v5 >> 16)),    accy);
      accx = fmaf(w6, b2f((unsigned short)(v6 & 0xffff)), accx);
      accy = fmaf(w6, b2f((unsigned short)(v6 >> 16)),    accy);
      accx = fmaf(w7, b2f((unsigned short)(v7 & 0xffff)), accx);
      accy = fmaf(w7, b2f((unsigned short)(v7 >> 16)),    accy);
    }
    for (; j < c2; j++) {
      int   sj = __shfl(my.x, j);
      float wj = __int_as_float(__shfl(my.y, j));
      unsigned v = *(const unsigned*)&xw1b[(size_t)sj * NHID + f0];
      accx = fmaf(wj, b2f((unsigned short)(v & 0xffff)), accx);
      accy = fmaf(wj, b2f((unsigned short)(v >> 16)),    accy);
    }
  }
  accx += b1[f0];
  accy += b1[f0 + 1];
  unsigned po = ((unsigned)f2b(fmaxf(accy, 0.f)) << 16) | f2b(fmaxf(accx, 0.f));
  *(unsigned*)&h[(size_t)node * NHID + f0] = po;
}

// ---------------- GEMM2: hw2 = h @ W2  via MFMA, 64x64 tile, K=256 ----------------

__global__ __launch_bounds__(256) void gemm2_k(const unsigned short* __restrict__ h,
                                               const unsigned short* __restrict__ w2t,
                                               float* __restrict__ hw2) {
  __shared__ short8 As[64 * 4];
  __shared__ short8 Bs[64 * 4];

  const int t  = threadIdx.x;
  const int bm = blockIdx.x * 64;
  const int l  = t & 63;
  const int wv = t >> 6;
  const int wr = wv >> 1, wc = wv & 1;
  const int srow = t >> 2, sslot = t & 3;

  const floatx4 zero = {0.f, 0.f, 0.f, 0.f};
  floatx4 acc[2][2];
  acc[0][0] = zero; acc[0][1] = zero; acc[1][0] = zero; acc[1][1] = zero;

  const int q = l >> 4;

  for (int k0 = 0; k0 < NHID; k0 += 32) {
    short8 av = *(const short8*)&h  [(size_t)(bm + srow) * NHID + k0 + sslot * 8];
    short8 bv = *(const short8*)&w2t[(size_t)srow * NHID + k0 + sslot * 8];
    __syncthreads();
    As[srow * 4 + (sslot ^ (srow & 3))] = av;
    Bs[srow * 4 + (sslot ^ (srow & 3))] = bv;
    __syncthreads();

    short8 af[2], bf2[2];
#pragma unroll
    for (int mi = 0; mi < 2; mi++) {
      int ar = wr * 32 + mi * 16 + (l & 15);
      af[mi] = As[ar * 4 + (q ^ (ar & 3))];
    }
#pragma unroll
    for (int ni = 0; ni < 2; ni++) {
      int bc = wc * 32 + ni * 16 + (l & 15);
      bf2[ni] = Bs[bc * 4 + (q ^ (bc & 3))];
    }
#pragma unroll
    for (int mi = 0; mi < 2; mi++)
#pragma unroll
      for (int ni = 0; ni < 2; ni++)
        acc[mi][ni] = __builtin_amdgcn_mfma_f32_16x16x32_bf16(af[mi], bf2[ni], acc[mi][ni], 0, 0, 0);
  }

#pragma unroll
  for (int mi = 0; mi < 2; mi++)
#pragma unroll
    for (int ni = 0; ni < 2; ni++) {
      int row = bm + wr * 32 + mi * 16 + (l >> 4) * 4;
      int col = wc * 32 + ni * 16 + (l & 15);
#pragma unroll
      for (int r = 0; r < 4; r++)
        hw2[(size_t)(row + r) * 64 + col] = acc[mi][ni][r];
    }
}

// ---------------- SpMM2 + b2 + log_softmax -> out (4 waves = 4 nodes/block) ----------------

__global__ __launch_bounds__(256) void spmm2_k(const int* __restrict__ cnt,
                                               const int2* __restrict__ epk,
                                               const float* __restrict__ hw2,
                                               const float* __restrict__ b2,
                                               float* __restrict__ out) {
  int wave = threadIdx.x >> 6;
  int lane = threadIdx.x & 63;
  int i    = blockIdx.x * 4 + wave;
  bool act = (lane < NCLASS);
  int e0 = i * SLOT;
  int n  = cnt[i];
  float acc = act ? b2[lane] : 0.f;
  for (int base = 0; base < n; base += 64) {
    int c2 = n - base; if (c2 > 64) c2 = 64;
    int2 my = make_int2(0, 0);
    if (lane < c2) my = epk[e0 + base + lane];
    int j = 0;
    for (; j + 8 <= c2; j += 8) {
      int   s0 = __shfl(my.x, j + 0); float w0 = __int_as_float(__shfl(my.y, j + 0));
      int   s1 = __shfl(my.x, j + 1); float w1 = __int_as_float(__shfl(my.y, j + 1));
      int   s2 = __shfl(my.x, j + 2); float w2 = __int_as_float(__shfl(my.y, j + 2));
      int   s3 = __shfl(my.x, j + 3); float w3 = __int_as_float(__shfl(my.y, j + 3));
      int   s4 = __shfl(my.x, j + 4); float w4 = __int_as_float(__shfl(my.y, j + 4));
      int   s5 = __shfl(my.x, j + 5); float w5 = __int_as_float(__shfl(my.y, j + 5));
      int   s6 = __shfl(my.x, j + 6); float w6 = __int_as_float(__shfl(my.y, j + 6));
      int   s7 = __shfl(my.x, j + 7); float w7 = __int_as_float(__shfl(my.y, j + 7));
      if (act) {
        float v0 = hw2[(size_t)s0 * 64 + lane];
        float v1 = hw2[(size_t)s1 * 64 + lane];
        float v2 = hw2[(size_t)s2 * 64 + lane];
        float v3 = hw2[(size_t)s3 * 64 + lane];
        float v4 = hw2[(size_t)s4 * 64 + lane];
        float v5 = hw2[(size_t)s5 * 64 + lane];
        float v6 = hw2[(size_t)s6 * 64 + lane];
        float v7 = hw2[(size_t)s7 * 64 + lane];
        acc = fmaf(w0, v0, acc); acc = fmaf(w1, v1, acc);
        acc = fmaf(w2, v2, acc); acc = fmaf(w3, v3, acc);
        acc = fmaf(w4, v4, acc); acc = fmaf(w5, v5, acc);
        acc = fmaf(w6, v6, acc); acc = fmaf(w7, v7, acc);
      }
    }
    for (; j < c2; j++) {
      int   sj = __shfl(my.x, j);
      float wj = __int_as_float(__shfl(my.y, j));
      if (act) acc = fmaf(wj, hw2[(size_t)sj * 64 + lane], acc);
    }
  }
  float v = act ? acc : -INFINITY;
#pragma unroll
  for (int o = 32; o > 0; o >>= 1) v = fmaxf(v, __shfl_xor(v, o));
  float m  = v;
  float ex = act ? expf(acc - m) : 0.f;
  float s  = ex;
#pragma unroll
  for (int o = 32; o > 0; o >>= 1) s += __shfl_xor(s, o);
  float ls = logf(s);
  if (act) out[(size_t)i * NCLASS + lane] = acc - m - ls;
}

// ---------------- launcher ----------------

static inline size_t align256(size_t v) { return (v + 255) & ~(size_t)255; }

extern "C" void kernel_launch(void* const* d_in, const int* in_sizes, int n_in,
                              void* d_out, int out_size, void* d_ws, size_t ws_size,
                              hipStream_t stream) {
  const float* x        = (const float*)d_in[0];
  const int*   edge_src = (const int*)  d_in[1];
  const int*   edge_dst = (const int*)  d_in[2];
  const float* edge_w   = (const float*)d_in[3];
  const float* W1       = (const float*)d_in[4];
  const float* b1       = (const float*)d_in[5];
  const float* W2       = (const float*)d_in[6];
  const float* b2       = (const float*)d_in[7];
  float* out = (float*)d_out;

  char* ws = (char*)d_ws;
  size_t off = 0;
  unsigned short* xb   = (unsigned short*)(ws + off); off = align256(off + (size_t)MPAD * NFEAT * 2);
  unsigned short* w1t  = (unsigned short*)(ws + off); off = align256(off + (size_t)NFEAT * NHID * 2);
  unsigned short* w2t  = (unsigned short*)(ws + off); off = align256(off + (size_t)64 * NHID * 2);
  unsigned short* xw1b = (unsigned short*)(ws + off); off = align256(off + (size_t)MPAD * NHID * 2);
  unsigned short* h    = (unsigned short*)(ws + off); off = align256(off + (size_t)MPAD * NHID * 2);
  float* hw2 = (float*)(ws + off); off = align256(off + (size_t)MPAD * 64 * 4);
  int*   cnt = (int*)  (ws + off); off = align256(off + (size_t)N_NODES * 4);
  int2*  epk = (int2*) (ws + off); off = align256(off + (size_t)N_NODES * SLOT * 8);   // 7.68 MB

  const int PREP_ITEMS = MPAD * NFEAT / 4 + NFEAT * NHID + 64 * NHID;
  prep_k<<<(PREP_ITEMS + 255) / 256, 256, 0, stream>>>(x, W1, W2, xb, w1t, w2t, cnt);

  scatter_gemm1_k<<<EB + G1X * G1Y, 256, 0, stream>>>(edge_src, edge_dst, edge_w,
                                                      cnt, epk, xb, w1t, xw1b);

  spmm1_k<<<5000, 256, 0, stream>>>(cnt, epk, xw1b, b1, h);

  gemm2_k<<<MPAD / 64, 256, 0, stream>>>(h, w2t, hw2);

  spmm2_k<<<2500, 256, 0, stream>>>(cnt, epk, hw2, b2, out);
}

// Round 9
// 78.550 us; speedup vs baseline: 3.0459x; 1.0447x over previous
//
#include <hip/hip_runtime.h>
#include <hip/hip_bf16.h>
#include <math.h>

#define N_NODES 10000
#define MPAD    10112      // 79 * 128
#define N_EDGES 320000
#define NFEAT   512
#define NHID    256
#define NCLASS  40
#define SLOT    96         // max deg bound: Binom(320K,1e-4) max ~55; P(>96) ~ 0
#define EB      ((N_EDGES + 255) / 256)   // 1250
#define G1X     (MPAD / 128)              // 79
#define NG1     (G1X * (NHID / 128))      // 158 gemm1 blocks

typedef short  short8  __attribute__((ext_vector_type(8)));
typedef float  floatx4 __attribute__((ext_vector_type(4)));

__device__ __forceinline__ unsigned short f2b(float f) {
  __hip_bfloat16 h = __float2bfloat16(f);
  unsigned short u; __builtin_memcpy(&u, &h, 2); return u;
}
__device__ __forceinline__ float b2f(unsigned short u) {
  return __uint_as_float(((unsigned)u) << 16);
}
__device__ __forceinline__ short8 pack8(float4 a, float4 b) {
  short8 r;
  r[0] = (short)f2b(a.x); r[1] = (short)f2b(a.y); r[2] = (short)f2b(a.z); r[3] = (short)f2b(a.w);
  r[4] = (short)f2b(b.x); r[5] = (short)f2b(b.y); r[6] = (short)f2b(b.z); r[7] = (short)f2b(b.w);
  return r;
}

// ---------------- prep: W1->bf16 transposed, W2->bf16 transposed+padded, cnt->0 ----

__global__ __launch_bounds__(256) void prep_k(const float* __restrict__ W1,
                                              const float* __restrict__ W2,
                                              unsigned short* __restrict__ w1t,
                                              unsigned short* __restrict__ w2t,
                                              int* __restrict__ cnt) {
  int tid = blockIdx.x * 256 + threadIdx.x;
  if (tid < N_NODES) cnt[tid] = 0;
  const int nw1 = NFEAT * NHID;              // 131,072
  if (tid < nw1) {
    int k = tid / NHID, n = tid % NHID;        // coalesced read of W1
    w1t[n * NFEAT + k] = f2b(W1[tid]);         // transposed bf16 write
  } else {
    int j = tid - nw1;
    if (j < 64 * NHID) {
      int n = j >> 8;                          // out-col 0..63
      int k = j & 255;                         // k 0..255
      w2t[j] = (n < NCLASS) ? f2b(W2[k * NCLASS + n]) : (unsigned short)0;
    }
  }
}

// ---------------- fused: GEMM1 128x128 MFMA (blocks < NG1)  ||  slot-scatter ----------------
// gemm1 stages A from f32 x directly (in-register bf16 convert); no xb pass.
// Slot-CSR: node i's edges at epk[i*SLOT .. i*SLOT+cnt[i]).

__global__ __launch_bounds__(256) void gemm1_scatter_k(
    const float* __restrict__ x, const unsigned short* __restrict__ w1t,
    unsigned short* __restrict__ xw1b,
    const int* __restrict__ src, const int* __restrict__ dst,
    const float* __restrict__ w, int* __restrict__ cnt, int2* __restrict__ epk) {
  if (blockIdx.x >= NG1) {
    int e = (blockIdx.x - NG1) * 256 + threadIdx.x;
    if (e < N_EDGES) {
      int d = dst[e];
      int p = atomicAdd(&cnt[d], 1);
      int2 pk; pk.x = src[e]; pk.y = __float_as_int(w[e]);
      epk[d * SLOT + p] = pk;
    }
    return;
  }
  __shared__ short8 As[128 * 4];   // 8 KB
  __shared__ short8 Bs[128 * 4];   // 8 KB

  const int b  = blockIdx.x;
  const int bx = b % G1X;
  const int by = b / G1X;
  const int bm = bx * 128;
  const int bn = by * 128;
  const int t  = threadIdx.x;
  const int l  = t & 63;
  const int wv = t >> 6;
  const int wr = wv >> 1, wc = wv & 1;

  const int rowX = t >> 1;            // 0..127
  const int sX   = (t & 1) * 2;       // slots sX, sX+1

  const floatx4 zero = {0.f, 0.f, 0.f, 0.f};
  floatx4 acc[4][4];
#pragma unroll
  for (int mi = 0; mi < 4; mi++)
#pragma unroll
    for (int ni = 0; ni < 4; ni++) acc[mi][ni] = zero;

  const int q = l >> 4;

  for (int k0 = 0; k0 < NFEAT; k0 += 32) {
    int arow = bm + rowX;
    float4 xa0 = make_float4(0.f, 0.f, 0.f, 0.f), xa1 = xa0, xa2 = xa0, xa3 = xa0;
    if (arow < N_NODES) {
      const float* xp = &x[(size_t)arow * NFEAT + k0 + sX * 8];
      xa0 = *(const float4*)(xp);
      xa1 = *(const float4*)(xp + 4);
      xa2 = *(const float4*)(xp + 8);
      xa3 = *(const float4*)(xp + 12);
    }
    short8 a0 = pack8(xa0, xa1), a1 = pack8(xa2, xa3);
    short8 b0 = *(const short8*)&w1t[(size_t)(bn + rowX) * NFEAT + k0 + sX * 8];
    short8 b1v = *(const short8*)&w1t[(size_t)(bn + rowX) * NFEAT + k0 + sX * 8 + 8];
    __syncthreads();
    As[rowX * 4 + ((sX    ) ^ (rowX & 3))] = a0;
    As[rowX * 4 + ((sX + 1) ^ (rowX & 3))] = a1;
    Bs[rowX * 4 + ((sX    ) ^ (rowX & 3))] = b0;
    Bs[rowX * 4 + ((sX + 1) ^ (rowX & 3))] = b1v;
    __syncthreads();

    short8 af[4], bf[4];
#pragma unroll
    for (int mi = 0; mi < 4; mi++) {
      int ar = wr * 64 + mi * 16 + (l & 15);
      af[mi] = As[ar * 4 + (q ^ (ar & 3))];
    }
#pragma unroll
    for (int ni = 0; ni < 4; ni++) {
      int bc = wc * 64 + ni * 16 + (l & 15);
      bf[ni] = Bs[bc * 4 + (q ^ (bc & 3))];
    }
#pragma unroll
    for (int mi = 0; mi < 4; mi++)
#pragma unroll
      for (int ni = 0; ni < 4; ni++)
        acc[mi][ni] = __builtin_amdgcn_mfma_f32_16x16x32_bf16(af[mi], bf[ni], acc[mi][ni], 0, 0, 0);
  }

#pragma unroll
  for (int mi = 0; mi < 4; mi++)
#pragma unroll
    for (int ni = 0; ni < 4; ni++) {
      int row = bm + wr * 64 + mi * 16 + (l >> 4) * 4;
      int col = bn + wc * 64 + ni * 16 + (l & 15);
#pragma unroll
      for (int r = 0; r < 4; r++)
        xw1b[(size_t)(row + r) * NHID + col] = f2b(acc[mi][ni][r]);
    }
}

// ---------------- SpMM1: h = bf16(relu(A * xw1 + b1)) ----------------
// Pair-gather: lane = (edge parity hh)<<5 | feat-group f; lane gathers uint2
// (4 bf16) of edge (j+hh)'s row-slice; shfl_xor(32) combines parities.
// xcd>>2 = slice (2.57 MB, L2-resident), xcd&3 = node quarter. 4 nodes/block.

__global__ __launch_bounds__(256) void spmm1_k(const int* __restrict__ cnt,
                                               const int2* __restrict__ epk,
                                               const unsigned short* __restrict__ xw1b,
                                               const float* __restrict__ b1,
                                               unsigned short* __restrict__ h) {
  int bid     = blockIdx.x;
  int xcd     = bid & 7;
  int slice   = xcd >> 2;                 // 0..1
  int quarter = xcd & 3;                  // 0..3
  int wave    = threadIdx.x >> 6;
  int lane    = threadIdx.x & 63;
  int node    = (bid >> 3) * 4 + wave + quarter * 2500;
  int hh      = lane >> 5;                // edge parity
  int f       = lane & 31;                // feat group (4 feats)
  int fbase   = slice * 128 + f * 4;

  int e0 = node * SLOT;
  int n  = cnt[node];
  float a0 = 0.f, a1 = 0.f, a2 = 0.f, a3 = 0.f;
  for (int base = 0; base < n; base += 64) {
    int c2 = n - base; if (c2 > 64) c2 = 64;
    int2 my = make_int2(0, 0);
    if (lane < c2) my = epk[e0 + base + lane];
    int j = 0;
    for (; j + 8 <= c2; j += 8) {
#pragma unroll
      for (int p = 0; p < 4; p++) {
        int   idx = j + 2 * p + hh;
        int   s   = __shfl(my.x, idx);
        float wj  = __int_as_float(__shfl(my.y, idx));
        uint2 v = *(const uint2*)&xw1b[(size_t)s * NHID + fbase];
        a0 = fmaf(wj, b2f((unsigned short)(v.x & 0xffff)), a0);
        a1 = fmaf(wj, b2f((unsigned short)(v.x >> 16)),    a1);
        a2 = fmaf(wj, b2f((unsigned short)(v.y & 0xffff)), a2);
        a3 = fmaf(wj, b2f((unsigned short)(v.y >> 16)),    a3);
      }
    }
    for (; j < c2; j++) {
      int   s  = __shfl(my.x, j);
      float wj = __int_as_float(__shfl(my.y, j));
      if (hh == 0) {
        uint2 v = *(const uint2*)&xw1b[(size_t)s * NHID + fbase];
        a0 = fmaf(wj, b2f((unsigned short)(v.x & 0xffff)), a0);
        a1 = fmaf(wj, b2f((unsigned short)(v.x >> 16)),    a1);
        a2 = fmaf(wj, b2f((unsigned short)(v.y & 0xffff)), a2);
        a3 = fmaf(wj, b2f((unsigned short)(v.y >> 16)),    a3);
      }
    }
  }
  a0 += __shfl_xor(a0, 32);
  a1 += __shfl_xor(a1, 32);
  a2 += __shfl_xor(a2, 32);
  a3 += __shfl_xor(a3, 32);
  if (hh == 0) {
    a0 = fmaxf(a0 + b1[fbase + 0], 0.f);
    a1 = fmaxf(a1 + b1[fbase + 1], 0.f);
    a2 = fmaxf(a2 + b1[fbase + 2], 0.f);
    a3 = fmaxf(a3 + b1[fbase + 3], 0.f);
    uint2 po;
    po.x = ((unsigned)f2b(a1) << 16) | f2b(a0);
    po.y = ((unsigned)f2b(a3) << 16) | f2b(a2);
    *(uint2*)&h[(size_t)node * NHID + fbase] = po;
  }
}

// ---------------- GEMM2: hw2 = h @ W2  via MFMA, 64x64 tile, K=256 ----------------

__global__ __launch_bounds__(256) void gemm2_k(const unsigned short* __restrict__ h,
                                               const unsigned short* __restrict__ w2t,
                                               float* __restrict__ hw2) {
  __shared__ short8 As[64 * 4];
  __shared__ short8 Bs[64 * 4];

  const int t  = threadIdx.x;
  const int bm = blockIdx.x * 64;
  const int l  = t & 63;
  const int wv = t >> 6;
  const int wr = wv >> 1, wc = wv & 1;
  const int srow = t >> 2, sslot = t & 3;

  const floatx4 zero = {0.f, 0.f, 0.f, 0.f};
  floatx4 acc[2][2];
  acc[0][0] = zero; acc[0][1] = zero; acc[1][0] = zero; acc[1][1] = zero;

  const int q = l >> 4;

  for (int k0 = 0; k0 < NHID; k0 += 32) {
    short8 av = *(const short8*)&h  [(size_t)(bm + srow) * NHID + k0 + sslot * 8];
    short8 bv = *(const short8*)&w2t[(size_t)srow * NHID + k0 + sslot * 8];
    __syncthreads();
    As[srow * 4 + (sslot ^ (srow & 3))] = av;
    Bs[srow * 4 + (sslot ^ (srow & 3))] = bv;
    __syncthreads();

    short8 af[2], bf2[2];
#pragma unroll
    for (int mi = 0; mi < 2; mi++) {
      int ar = wr * 32 + mi * 16 + (l & 15);
      af[mi] = As[ar * 4 + (q ^ (ar & 3))];
    }
#pragma unroll
    for (int ni = 0; ni < 2; ni++) {
      int bc = wc * 32 + ni * 16 + (l & 15);
      bf2[ni] = Bs[bc * 4 + (q ^ (bc & 3))];
    }
#pragma unroll
    for (int mi = 0; mi < 2; mi++)
#pragma unroll
      for (int ni = 0; ni < 2; ni++)
        acc[mi][ni] = __builtin_amdgcn_mfma_f32_16x16x32_bf16(af[mi], bf2[ni], acc[mi][ni], 0, 0, 0);
  }

#pragma unroll
  for (int mi = 0; mi < 2; mi++)
#pragma unroll
    for (int ni = 0; ni < 2; ni++) {
      int row = bm + wr * 32 + mi * 16 + (l >> 4) * 4;
      int col = wc * 32 + ni * 16 + (l & 15);
#pragma unroll
      for (int r = 0; r < 4; r++)
        hw2[(size_t)(row + r) * 64 + col] = acc[mi][ni][r];
    }
}

// ---------------- SpMM2 + b2 + log_softmax -> out ----------------
// Pair-gather: lane = hh<<5 | c; lane gathers float2 (2 classes) of edge
// (j+hh)'s hw2 row; shfl_xor(32) combines; softmax over 5-step shfl_xor.

__global__ __launch_bounds__(256) void spmm2_k(const int* __restrict__ cnt,
                                               const int2* __restrict__ epk,
                                               const float* __restrict__ hw2,
                                               const float* __restrict__ b2,
                                               float* __restrict__ out) {
  int wave = threadIdx.x >> 6;
  int lane = threadIdx.x & 63;
  int i    = blockIdx.x * 4 + wave;
  int hh   = lane >> 5;
  int c    = lane & 31;                 // classes c*2, c*2+1
  bool act = (c * 2 < NCLASS);          // c < 20
  int e0 = i * SLOT;
  int n  = cnt[i];
  float a0 = 0.f, a1 = 0.f;
  for (int base = 0; base < n; base += 64) {
    int c2 = n - base; if (c2 > 64) c2 = 64;
    int2 my = make_int2(0, 0);
    if (lane < c2) my = epk[e0 + base + lane];
    int j = 0;
    for (; j + 8 <= c2; j += 8) {
#pragma unroll
      for (int p = 0; p < 4; p++) {
        int   idx = j + 2 * p + hh;
        int   s   = __shfl(my.x, idx);
        float wj  = __int_as_float(__shfl(my.y, idx));
        float2 v = *(const float2*)&hw2[(size_t)s * 64 + c * 2];
        a0 = fmaf(wj, v.x, a0);
        a1 = fmaf(wj, v.y, a1);
      }
    }
    for (; j < c2; j++) {
      int   s  = __shfl(my.x, j);
      float wj = __int_as_float(__shfl(my.y, j));
      if (hh == 0) {
        float2 v = *(const float2*)&hw2[(size_t)s * 64 + c * 2];
        a0 = fmaf(wj, v.x, a0);
        a1 = fmaf(wj, v.y, a1);
      }
    }
  }
  a0 += __shfl_xor(a0, 32);
  a1 += __shfl_xor(a1, 32);
  if (act) { a0 += b2[c * 2]; a1 += b2[c * 2 + 1]; }
  float mv = act ? fmaxf(a0, a1) : -INFINITY;
#pragma unroll
  for (int o = 16; o > 0; o >>= 1) mv = fmaxf(mv, __shfl_xor(mv, o));
  float ex = act ? (expf(a0 - mv) + expf(a1 - mv)) : 0.f;
#pragma unroll
  for (int o = 16; o > 0; o >>= 1) ex += __shfl_xor(ex, o);
  float ls = logf(ex);
  if (act && hh == 0) {
    float2 o2; o2.x = a0 - mv - ls; o2.y = a1 - mv - ls;
    *(float2*)&out[(size_t)i * NCLASS + c * 2] = o2;
  }
}

// ---------------- launcher ----------------

static inline size_t align256(size_t v) { return (v + 255) & ~(size_t)255; }

extern "C" void kernel_launch(void* const* d_in, const int* in_sizes, int n_in,
                              void* d_out, int out_size, void* d_ws, size_t ws_size,
                              hipStream_t stream) {
  const float* x        = (const float*)d_in[0];
  const int*   edge_src = (const int*)  d_in[1];
  const int*   edge_dst = (const int*)  d_in[2];
  const float* edge_w   = (const float*)d_in[3];
  const float* W1       = (const float*)d_in[4];
  const float* b1       = (const float*)d_in[5];
  const float* W2       = (const float*)d_in[6];
  const float* b2       = (const float*)d_in[7];
  float* out = (float*)d_out;

  char* ws = (char*)d_ws;
  size_t off = 0;
  unsigned short* w1t  = (unsigned short*)(ws + off); off = align256(off + (size_t)NFEAT * NHID * 2);
  unsigned short* w2t  = (unsigned short*)(ws + off); off = align256(off + (size_t)64 * NHID * 2);
  unsigned short* xw1b = (unsigned short*)(ws + off); off = align256(off + (size_t)MPAD * NHID * 2);
  unsigned short* h    = (unsigned short*)(ws + off); off = align256(off + (size_t)MPAD * NHID * 2);
  float* hw2 = (float*)(ws + off); off = align256(off + (size_t)MPAD * 64 * 4);
  int*   cnt = (int*)  (ws + off); off = align256(off + (size_t)N_NODES * 4);
  int2*  epk = (int2*) (ws + off); off = align256(off + (size_t)N_NODES * SLOT * 8);   // 7.68 MB

  const int PREP_ITEMS = NFEAT * NHID + 64 * NHID;
  prep_k<<<(PREP_ITEMS + 255) / 256, 256, 0, stream>>>(W1, W2, w1t, w2t, cnt);

  gemm1_scatter_k<<<NG1 + EB, 256, 0, stream>>>(x, w1t, xw1b,
                                                edge_src, edge_dst, edge_w, cnt, epk);

  spmm1_k<<<5000, 256, 0, stream>>>(cnt, epk, xw1b, b1, h);

  gemm2_k<<<157, 256, 0, stream>>>(h, w2t, hw2);

  spmm2_k<<<2500, 256, 0, stream>>>(cnt, epk, hw2, b2, out);
}

// Round 11
// 76.457 us; speedup vs baseline: 3.1293x; 1.0274x over previous
//
#include <hip/hip_runtime.h>
#include <hip/hip_bf16.h>
#include <math.h>

#define N_NODES 10000
#define MPAD    10112      // 79 * 128
#define N_EDGES 320000
#define NFEAT   512
#define NHID    256
#define NCLASS  40
#define SLOT    96         // max deg bound: Binom(320K,1e-4) max ~55; P(>96) ~ 0
#define CSTRIDE 16         // one counter per 64B line (atomic line-serialization fix)
#define NBM1    158        // gemm1 m-tiles (64 rows each)

typedef short  short8  __attribute__((ext_vector_type(8)));
typedef float  floatx4 __attribute__((ext_vector_type(4)));

__device__ __forceinline__ unsigned short f2b(float f) {
  __hip_bfloat16 h = __float2bfloat16(f);
  unsigned short u; __builtin_memcpy(&u, &h, 2); return u;
}
__device__ __forceinline__ float b2f(unsigned short u) {
  return __uint_as_float(((unsigned)u) << 16);
}
__device__ __forceinline__ short8 pack8(float4 a, float4 b) {
  short8 r;
  r[0] = (short)f2b(a.x); r[1] = (short)f2b(a.y); r[2] = (short)f2b(a.z); r[3] = (short)f2b(a.w);
  r[4] = (short)f2b(b.x); r[5] = (short)f2b(b.y); r[6] = (short)f2b(b.z); r[7] = (short)f2b(b.w);
  return r;
}

// ---------------- prep: W1->bf16 transposed, W2->bf16 transposed+padded,
//                  cnt (padded, 160000 ints) -> 0 ----------------

__global__ __launch_bounds__(256) void prep_k(const float* __restrict__ W1,
                                              const float* __restrict__ W2,
                                              unsigned short* __restrict__ w1t,
                                              unsigned short* __restrict__ w2t,
                                              int* __restrict__ cnt) {
  int tid = blockIdx.x * 256 + threadIdx.x;
  if (tid < N_NODES * CSTRIDE) cnt[tid] = 0;
  const int nw1 = NFEAT * NHID;              // 131,072
  if (tid < nw1) {
    int k = tid / NHID, n = tid % NHID;        // coalesced read of W1
    w1t[n * NFEAT + k] = f2b(W1[tid]);         // transposed bf16 write
  } else if (tid < nw1 + 64 * NHID) {
    int j = tid - nw1;
    int n = j >> 8;                            // out-col 0..63
    int k = j & 255;                           // k 0..255
    w2t[j] = (n < NCLASS) ? f2b(W2[k * NCLASS + n]) : (unsigned short)0;
  }
}

// ---------------- slot-scatter: epk[d*SLOT + atomic-rank] ----------------
// counters padded to 64B lines: atomicAdd(&cnt[d<<4]).

__global__ __launch_bounds__(1024) void scatter_k(const int* __restrict__ src,
                                                  const int* __restrict__ dst,
                                                  const float* __restrict__ w,
                                                  int* __restrict__ cnt,
                                                  int2* __restrict__ epk) {
  int e = blockIdx.x * 1024 + threadIdx.x;
  if (e < N_EDGES) {
    int d = dst[e];
    int p = atomicAdd(&cnt[d << 4], 1);
    int2 pk; pk.x = src[e]; pk.y = __float_as_int(w[e]);
    epk[d * SLOT + p] = pk;
  }
}

// ---------------- GEMM1: xw1b = bf16(x @ W1), 64x128 tile, double-buffered ----------------
// A staged from f32 x with in-register bf16 pack. 316 blocks (158 m x 2 n).
// One barrier per K-step; loads for step s+1 issue before compute of step s.

__global__ __launch_bounds__(256) void gemm1_k(const float* __restrict__ x,
                                               const unsigned short* __restrict__ w1t,
                                               unsigned short* __restrict__ xw1b) {
  __shared__ short8 As[2][64 * 4];    // 8 KB
  __shared__ short8 Bs[2][128 * 4];   // 16 KB

  const int t  = threadIdx.x;
  const int l  = t & 63;
  const int wc = t >> 6;                    // wave 0..3 -> col strip of 32
  const int bm = (blockIdx.x % NBM1) * 64;
  const int bn = (blockIdx.x / NBM1) * 128;

  const int rowA = t >> 2, sA = t & 3;          // A: 8 floats -> 1 short8 slot
  const int rowB = t >> 1, sB = (t & 1) * 2;    // B: 2 short8 slots

  const float4 z4 = make_float4(0.f, 0.f, 0.f, 0.f);
  const floatx4 zero = {0.f, 0.f, 0.f, 0.f};
  floatx4 acc[4][2];
#pragma unroll
  for (int mi = 0; mi < 4; mi++) { acc[mi][0] = zero; acc[mi][1] = zero; }

  const int q = l >> 4;
  const bool arok = (bm + rowA) < N_NODES;
  const float* xrow = &x[(size_t)(bm + rowA) * NFEAT + sA * 8];
  const unsigned short* brow = &w1t[(size_t)(bn + rowB) * NFEAT + sB * 8];

  // prologue: stage k0 = 0 into buffer 0
  {
    float4 a0 = z4, a1 = z4;
    if (arok) { a0 = *(const float4*)(xrow); a1 = *(const float4*)(xrow + 4); }
    short8 b0 = *(const short8*)(brow);
    short8 b1 = *(const short8*)(brow + 8);
    As[0][rowA * 4 + (sA ^ (rowA & 3))] = pack8(a0, a1);
    Bs[0][rowB * 4 + ((sB    ) ^ (rowB & 3))] = b0;
    Bs[0][rowB * 4 + ((sB + 1) ^ (rowB & 3))] = b1;
  }

  for (int s = 0; s < 16; s++) {
    __syncthreads();                      // buf[s&1] staged; prior readers done
    const int cur = s & 1;
    float4 na0 = z4, na1 = z4;
    short8 nb0, nb1;
    const bool more = (s < 15);
    if (more) {
      const int k1 = (s + 1) * 32;
      if (arok) { na0 = *(const float4*)(xrow + k1); na1 = *(const float4*)(xrow + k1 + 4); }
      nb0 = *(const short8*)(brow + k1);
      nb1 = *(const short8*)(brow + k1 + 8);
    }

    short8 af[4], bf[2];
#pragma unroll
    for (int mi = 0; mi < 4; mi++) {
      int ar = mi * 16 + (l & 15);
      af[mi] = As[cur][ar * 4 + (q ^ (ar & 3))];
    }
#pragma unroll
    for (int ni = 0; ni < 2; ni++) {
      int bc = wc * 32 + ni * 16 + (l & 15);
      bf[ni] = Bs[cur][bc * 4 + (q ^ (bc & 3))];
    }
#pragma unroll
    for (int mi = 0; mi < 4; mi++)
#pragma unroll
      for (int ni = 0; ni < 2; ni++)
        acc[mi][ni] = __builtin_amdgcn_mfma_f32_16x16x32_bf16(af[mi], bf[ni], acc[mi][ni], 0, 0, 0);

    if (more) {
      const int nxt = cur ^ 1;
      As[nxt][rowA * 4 + (sA ^ (rowA & 3))] = pack8(na0, na1);
      Bs[nxt][rowB * 4 + ((sB    ) ^ (rowB & 3))] = nb0;
      Bs[nxt][rowB * 4 + ((sB + 1) ^ (rowB & 3))] = nb1;
    }
  }

#pragma unroll
  for (int mi = 0; mi < 4; mi++)
#pragma unroll
    for (int ni = 0; ni < 2; ni++) {
      int row = bm + mi * 16 + (l >> 4) * 4;
      int col = bn + wc * 32 + ni * 16 + (l & 15);
#pragma unroll
      for (int r = 0; r < 4; r++)
        xw1b[(size_t)(row + r) * NHID + col] = f2b(acc[mi][ni][r]);
    }
}

// ---------------- SpMM1: h = bf16(relu(A * xw1 + b1)) ----------------
// Pair-gather: lane = hh<<5 | f; uint2 gather (4 bf16); shfl_xor(32) combine.
// xcd>>2 = slice (L2-resident), xcd&3 = node quarter. 4 nodes/block.

__global__ __launch_bounds__(256) void spmm1_k(const int* __restrict__ cnt,
                                               const int2* __restrict__ epk,
                                               const unsigned short* __restrict__ xw1b,
                                               const float* __restrict__ b1,
                                               unsigned short* __restrict__ h) {
  int bid     = blockIdx.x;
  int xcd     = bid & 7;
  int slice   = xcd >> 2;
  int quarter = xcd & 3;
  int wave    = threadIdx.x >> 6;
  int lane    = threadIdx.x & 63;
  int node    = (bid >> 3) * 4 + wave + quarter * 2500;
  int hh      = lane >> 5;
  int f       = lane & 31;
  int fbase   = slice * 128 + f * 4;

  int e0 = node * SLOT;
  int n  = cnt[node << 4];
  float a0 = 0.f, a1 = 0.f, a2 = 0.f, a3 = 0.f;
  for (int base = 0; base < n; base += 64) {
    int c2 = n - base; if (c2 > 64) c2 = 64;
    int2 my = make_int2(0, 0);
    if (lane < c2) my = epk[e0 + base + lane];
    int j = 0;
    for (; j + 8 <= c2; j += 8) {
#pragma unroll
      for (int p = 0; p < 4; p++) {
        int   idx = j + 2 * p + hh;
        int   s   = __shfl(my.x, idx);
        float wj  = __int_as_float(__shfl(my.y, idx));
        uint2 v = *(const uint2*)&xw1b[(size_t)s * NHID + fbase];
        a0 = fmaf(wj, b2f((unsigned short)(v.x & 0xffff)), a0);
        a1 = fmaf(wj, b2f((unsigned short)(v.x >> 16)),    a1);
        a2 = fmaf(wj, b2f((unsigned short)(v.y & 0xffff)), a2);
        a3 = fmaf(wj, b2f((unsigned short)(v.y >> 16)),    a3);
      }
    }
    for (; j < c2; j++) {
      int   s  = __shfl(my.x, j);
      float wj = __int_as_float(__shfl(my.y, j));
      if (hh == 0) {
        uint2 v = *(const uint2*)&xw1b[(size_t)s * NHID + fbase];
        a0 = fmaf(wj, b2f((unsigned short)(v.x & 0xffff)), a0);
        a1 = fmaf(wj, b2f((unsigned short)(v.x >> 16)),    a1);
        a2 = fmaf(wj, b2f((unsigned short)(v.y & 0xffff)), a2);
        a3 = fmaf(wj, b2f((unsigned short)(v.y >> 16)),    a3);
      }
    }
  }
  a0 += __shfl_xor(a0, 32);
  a1 += __shfl_xor(a1, 32);
  a2 += __shfl_xor(a2, 32);
  a3 += __shfl_xor(a3, 32);
  if (hh == 0) {
    a0 = fmaxf(a0 + b1[fbase + 0], 0.f);
    a1 = fmaxf(a1 + b1[fbase + 1], 0.f);
    a2 = fmaxf(a2 + b1[fbase + 2], 0.f);
    a3 = fmaxf(a3 + b1[fbase + 3], 0.f);
    uint2 po;
    po.x = ((unsigned)f2b(a1) << 16) | f2b(a0);
    po.y = ((unsigned)f2b(a3) << 16) | f2b(a2);
    *(uint2*)&h[(size_t)node * NHID + fbase] = po;
  }
}

// ---------------- GEMM2: hw2 = h @ W2  via MFMA, 64x64 tile, K=256 ----------------

__global__ __launch_bounds__(256) void gemm2_k(const unsigned short* __restrict__ h,
                                               const unsigned short* __restrict__ w2t,
                                               float* __restrict__ hw2) {
  __shared__ short8 As[64 * 4];
  __shared__ short8 Bs[64 * 4];

  const int t  = threadIdx.x;
  const int bm = blockIdx.x * 64;
  const int l  = t & 63;
  const int wv = t >> 6;
  const int wr = wv >> 1, wc = wv & 1;
  const int srow = t >> 2, sslot = t & 3;

  const floatx4 zero = {0.f, 0.f, 0.f, 0.f};
  floatx4 acc[2][2];
  acc[0][0] = zero; acc[0][1] = zero; acc[1][0] = zero; acc[1][1] = zero;

  const int q = l >> 4;

  for (int k0 = 0; k0 < NHID; k0 += 32) {
    short8 av = *(const short8*)&h  [(size_t)(bm + srow) * NHID + k0 + sslot * 8];
    short8 bv = *(const short8*)&w2t[(size_t)srow * NHID + k0 + sslot * 8];
    __syncthreads();
    As[srow * 4 + (sslot ^ (srow & 3))] = av;
    Bs[srow * 4 + (sslot ^ (srow & 3))] = bv;
    __syncthreads();

    short8 af[2], bf2[2];
#pragma unroll
    for (int mi = 0; mi < 2; mi++) {
      int ar = wr * 32 + mi * 16 + (l & 15);
      af[mi] = As[ar * 4 + (q ^ (ar & 3))];
    }
#pragma unroll
    for (int ni = 0; ni < 2; ni++) {
      int bc = wc * 32 + ni * 16 + (l & 15);
      bf2[ni] = Bs[bc * 4 + (q ^ (bc & 3))];
    }
#pragma unroll
    for (int mi = 0; mi < 2; mi++)
#pragma unroll
      for (int ni = 0; ni < 2; ni++)
        acc[mi][ni] = __builtin_amdgcn_mfma_f32_16x16x32_bf16(af[mi], bf2[ni], acc[mi][ni], 0, 0, 0);
  }

#pragma unroll
  for (int mi = 0; mi < 2; mi++)
#pragma unroll
    for (int ni = 0; ni < 2; ni++) {
      int row = bm + wr * 32 + mi * 16 + (l >> 4) * 4;
      int col = wc * 32 + ni * 16 + (l & 15);
#pragma unroll
      for (int r = 0; r < 4; r++)
        hw2[(size_t)(row + r) * 64 + col] = acc[mi][ni][r];
    }
}

// ---------------- SpMM2 + b2 + log_softmax -> out ----------------

__global__ __launch_bounds__(256) void spmm2_k(const int* __restrict__ cnt,
                                               const int2* __restrict__ epk,
                                               const float* __restrict__ hw2,
                                               const float* __restrict__ b2,
                                               float* __restrict__ out) {
  int wave = threadIdx.x >> 6;
  int lane = threadIdx.x & 63;
  int i    = blockIdx.x * 4 + wave;
  int hh   = lane >> 5;
  int c    = lane & 31;                 // classes c*2, c*2+1
  bool act = (c * 2 < NCLASS);          // c < 20
  int e0 = i * SLOT;
  int n  = cnt[i << 4];
  float a0 = 0.f, a1 = 0.f;
  for (int base = 0; base < n; base += 64) {
    int c2 = n - base; if (c2 > 64) c2 = 64;
    int2 my = make_int2(0, 0);
    if (lane < c2) my = epk[e0 + base + lane];
    int j = 0;
    for (; j + 8 <= c2; j += 8) {
#pragma unroll
      for (int p = 0; p < 4; p++) {
        int   idx = j + 2 * p + hh;
        int   s   = __shfl(my.x, idx);
        float wj  = __int_as_float(__shfl(my.y, idx));
        float2 v = *(const float2*)&hw2[(size_t)s * 64 + c * 2];
        a0 = fmaf(wj, v.x, a0);
        a1 = fmaf(wj, v.y, a1);
      }
    }
    for (; j < c2; j++) {
      int   s  = __shfl(my.x, j);
      float wj = __int_as_float(__shfl(my.y, j));
      if (hh == 0) {
        float2 v = *(const float2*)&hw2[(size_t)s * 64 + c * 2];
        a0 = fmaf(wj, v.x, a0);
        a1 = fmaf(wj, v.y, a1);
      }
    }
  }
  a0 += __shfl_xor(a0, 32);
  a1 += __shfl_xor(a1, 32);
  if (act) { a0 += b2[c * 2]; a1 += b2[c * 2 + 1]; }
  float mv = act ? fmaxf(a0, a1) : -INFINITY;
#pragma unroll
  for (int o = 16; o > 0; o >>= 1) mv = fmaxf(mv, __shfl_xor(mv, o));
  float ex = act ? (expf(a0 - mv) + expf(a1 - mv)) : 0.f;
#pragma unroll
  for (int o = 16; o > 0; o >>= 1) ex += __shfl_xor(ex, o);
  float ls = logf(ex);
  if (act && hh == 0) {
    float2 o2; o2.x = a0 - mv - ls; o2.y = a1 - mv - ls;
    *(float2*)&out[(size_t)i * NCLASS + c * 2] = o2;
  }
}

// ---------------- launcher ----------------

static inline size_t align256(size_t v) { return (v + 255) & ~(size_t)255; }

extern "C" void kernel_launch(void* const* d_in, const int* in_sizes, int n_in,
                              void* d_out, int out_size, void* d_ws, size_t ws_size,
                              hipStream_t stream) {
  const float* x        = (const float*)d_in[0];
  const int*   edge_src = (const int*)  d_in[1];
  const int*   edge_dst = (const int*)  d_in[2];
  const float* edge_w   = (const float*)d_in[3];
  const float* W1       = (const float*)d_in[4];
  const float* b1       = (const float*)d_in[5];
  const float* W2       = (const float*)d_in[6];
  const float* b2       = (const float*)d_in[7];
  float* out = (float*)d_out;

  char* ws = (char*)d_ws;
  size_t off = 0;
  unsigned short* w1t  = (unsigned short*)(ws + off); off = align256(off + (size_t)NFEAT * NHID * 2);
  unsigned short* w2t  = (unsigned short*)(ws + off); off = align256(off + (size_t)64 * NHID * 2);
  unsigned short* xw1b = (unsigned short*)(ws + off); off = align256(off + (size_t)MPAD * NHID * 2);
  unsigned short* h    = (unsigned short*)(ws + off); off = align256(off + (size_t)MPAD * NHID * 2);
  float* hw2 = (float*)(ws + off); off = align256(off + (size_t)MPAD * 64 * 4);
  int*   cnt = (int*)  (ws + off); off = align256(off + (size_t)N_NODES * CSTRIDE * 4);  // 640 KB
  int2*  epk = (int2*) (ws + off); off = align256(off + (size_t)N_NODES * SLOT * 8);     // 7.68 MB

  const int PREP_ITEMS = N_NODES * CSTRIDE;   // 160000 >= weight items
  prep_k<<<(PREP_ITEMS + 255) / 256, 256, 0, stream>>>(W1, W2, w1t, w2t, cnt);

  scatter_k<<<(N_EDGES + 1023) / 1024, 1024, 0, stream>>>(edge_src, edge_dst, edge_w, cnt, epk);

  gemm1_k<<<NBM1 * 2, 256, 0, stream>>>(x, w1t, xw1b);

  spmm1_k<<<5000, 256, 0, stream>>>(cnt, epk, xw1b, b1, h);

  gemm2_k<<<157, 256, 0, stream>>>(h, w2t, hw2);

  spmm2_k<<<2500, 256, 0, stream>>>(cnt, epk, hw2, b2, out);
}